// Round 5
// baseline (346.960 us; speedup 1.0000x reference)
//
#include <hip/hip_runtime.h>
#include <cstdint>
#include <cstddef>

typedef __bf16 bf16;
typedef __attribute__((ext_vector_type(8))) __bf16 bf16x8;
typedef __attribute__((ext_vector_type(4))) __bf16 bf16x4;
typedef __attribute__((ext_vector_type(4))) float f32x4;

#define MFMA16 __builtin_amdgcn_mfma_f32_16x16x32_bf16

// async global -> LDS, 16B per lane. LDS dest is wave-uniform base + lane*16.
__device__ __forceinline__ void gload16(const bf16* g, bf16* l) {
    __builtin_amdgcn_global_load_lds(
        (const __attribute__((address_space(1))) uint32_t*)g,
        (__attribute__((address_space(3))) uint32_t*)l, 16, 0, 0);
}

// pack two f32 -> u32 of 2 bf16 (elem0 = lo bits)
__device__ __forceinline__ unsigned pk2(float lo, float hi) {
    union { bf16 h[2]; unsigned u; } c;
    c.h[0] = (bf16)lo; c.h[1] = (bf16)hi;
    return c.u;
}
// v_permlane32_swap_b32: a' = [a.lo | b.lo], b' = [a.hi | b.hi]
__device__ __forceinline__ void pl32swap(unsigned& a, unsigned& b) {
    asm volatile("v_permlane32_swap_b32 %0, %1" : "+v"(a), "+v"(b));
}
// raw v_exp_f32: 2^x
__device__ __forceinline__ float fexp2(float x) {
    float r;
    asm("v_exp_f32 %0, %1" : "=v"(r) : "v"(x));
    return r;
}

// bijective XCD chunk swizzle (nwg % 8 == 0)
__device__ __forceinline__ int xcd_swz(int id, int nwg) {
    return (id & 7) * (nwg >> 3) + (id >> 3);
}

// ---------------------------------------------------------------------------
// Tiled transpose + fp32->bf16 cast:  src [K][N] fp32  ->  dst [N][K] bf16
// ---------------------------------------------------------------------------
__global__ __launch_bounds__(256) void transpose_cast(
    const float* __restrict__ src, bf16* __restrict__ dst, int K, int N)
{
    __shared__ float t[32][33];
    const int n0 = blockIdx.x * 32, k0 = blockIdx.y * 32;
    const int tx = threadIdx.x, ty = threadIdx.y;
    #pragma unroll
    for (int i = ty; i < 32; i += 8)
        t[i][tx] = src[(size_t)(k0 + i) * N + n0 + tx];
    __syncthreads();
    #pragma unroll
    for (int i = ty; i < 32; i += 8)
        dst[(size_t)(n0 + i) * K + k0 + tx] = (bf16)t[tx][i];
}

// ---------------------------------------------------------------------------
// LayerNorm (D=1024) fp32 in -> bf16 out. One block (256 thr) per row.
// ---------------------------------------------------------------------------
__global__ __launch_bounds__(256) void ln_kernel(
    const float* __restrict__ x, const float* __restrict__ sc,
    const float* __restrict__ bi, bf16* __restrict__ y)
{
    const int row = blockIdx.x, tid = threadIdx.x;
    const f32x4 v = ((const f32x4*)(x + (size_t)row * 1024))[tid];
    float s  = v[0] + v[1] + v[2] + v[3];
    float s2 = v[0]*v[0] + v[1]*v[1] + v[2]*v[2] + v[3]*v[3];
    #pragma unroll
    for (int d = 1; d < 64; d <<= 1) {
        s  += __shfl_xor(s, d);
        s2 += __shfl_xor(s2, d);
    }
    __shared__ float red[8];
    if ((tid & 63) == 0) { red[tid >> 6] = s; red[4 + (tid >> 6)] = s2; }
    __syncthreads();
    s  = red[0] + red[1] + red[2] + red[3];
    s2 = red[4] + red[5] + red[6] + red[7];
    const float mu = s * (1.f / 1024.f);
    const float rstd = rsqrtf(s2 * (1.f / 1024.f) - mu * mu + 1e-6f);
    const f32x4 s4 = ((const f32x4*)sc)[tid];
    const f32x4 b4 = ((const f32x4*)bi)[tid];
    bf16x4 o;
    #pragma unroll
    for (int j = 0; j < 4; ++j)
        o[j] = (bf16)((v[j] - mu) * rstd * s4[j] + b4[j]);
    ((bf16x4*)(y + (size_t)row * 1024))[tid] = o;
}

// ---------------------------------------------------------------------------
// bf16 GEMM, 2-phase LDS dbuf, BK=64: C[M][N] = A[M][K] @ Bt[N][K]^T.
// Tile BM x BN (BM==BN), NW waves. Per K-step: issue next tile's
// global_load_lds FIRST, then ds_read+MFMA current (2 k-halves), then ONE
// __syncthreads (implicit vmcnt(0) lands the prefetch that flew under MFMA).
// EPI 0: QKV scatter (+bias; Q pre-scaled by 0.125*log2e); V written
//        TRANSPOSED to [Z][64][2048]. EPI 1: fp32 acc+bias+res.
// EPI 2: bf16 gelu(acc+bias) (sigmoid form).
// ---------------------------------------------------------------------------
template <int EPI, int BM, int BN, int NW>
__global__ __launch_bounds__(NW * 64, 2) void gemm_kernel(
    const bf16* __restrict__ A, const bf16* __restrict__ Bt,
    int M, int N, int K,
    const float* __restrict__ b0, const float* __restrict__ b1,
    const float* __restrict__ b2, const float* __restrict__ res,
    bf16* __restrict__ o0, bf16* __restrict__ o1, bf16* __restrict__ o2,
    float* __restrict__ of)
{
    constexpr int NRW = NW / 2;          // wave cols (2 or 4)
    constexpr int MR  = BM / 32;         // row frags/wave (4 or 8)
    constexpr int NR  = BN / 16 / NRW;   // col frags/wave (4)
    __shared__ bf16 As[2][BM * 64];
    __shared__ bf16 Bs[2][BN * 64];

    const int tid = threadIdx.x;
    const int wave = tid >> 6, lane = tid & 63;
    const int wr = (wave / NRW) * (MR * 16), wc = (wave % NRW) * (NR * 16);
    const int lr = lane & 15, lk = (lane >> 4) * 8;

    const int nwg = gridDim.x * gridDim.y;
    const int id = xcd_swz(blockIdx.y * gridDim.x + blockIdx.x, nwg);
    const int bm = (id / gridDim.x) * BM, bn = (id % gridDim.x) * BN;

    f32x4 acc[MR][NR] = {};

    // staging: 4 calls per operand; call c covers rows [c*8*NW, c*8*NW+8*NW)
    const int srow = tid >> 3;                 // + c*8*NW
    const int scol = (tid & 7) * 8;
    const bf16* Ag = A  + (size_t)(bm + srow) * K + scol;
    const bf16* Bg = Bt + (size_t)(bn + srow) * K + scol;

    auto stage = [&](int buf, int k0) {
        #pragma unroll
        for (int c = 0; c < 4; ++c)
            gload16(Ag + (size_t)(c * 8 * NW) * K + k0,
                    &As[buf][(c * 8 * NW) * 64] + (size_t)tid * 8);
        #pragma unroll
        for (int c = 0; c < 4; ++c)
            gload16(Bg + (size_t)(c * 8 * NW) * K + k0,
                    &Bs[buf][(c * 8 * NW) * 64] + (size_t)tid * 8);
    };

    const int nk = K >> 6;
    stage(0, 0);
    __syncthreads();
    int cur = 0;
    for (int i = 0; i < nk; ++i) {
        if (i + 1 < nk) stage(cur ^ 1, (i + 1) << 6);   // flies under MFMA
        #pragma unroll
        for (int kh = 0; kh < 2; ++kh) {
            const int ko = kh * 32 + lk;
            bf16x8 a[MR], b[NR];
            #pragma unroll
            for (int m = 0; m < MR; ++m)
                a[m] = *(const bf16x8*)&As[cur][(wr + m * 16 + lr) * 64 + ko];
            #pragma unroll
            for (int n = 0; n < NR; ++n)
                b[n] = *(const bf16x8*)&Bs[cur][(wc + n * 16 + lr) * 64 + ko];
            #pragma unroll
            for (int m = 0; m < MR; ++m)
                #pragma unroll
                for (int n = 0; n < NR; ++n)
                    acc[m][n] = MFMA16(a[m], b[n], acc[m][n], 0, 0, 0);
        }
        __syncthreads();   // implicit vmcnt(0): prefetch landed; cur free
        cur ^= 1;
    }

    const int rbase = bm + wr + ((lane >> 4) << 2);
    const int cbase = bn + wc + lr;
    #pragma unroll
    for (int m = 0; m < MR; ++m) {
        #pragma unroll
        for (int n = 0; n < NR; ++n) {
            const f32x4 v = acc[m][n];
            #pragma unroll
            for (int r = 0; r < 4; ++r) {
                const int row = rbase + m * 16 + r;
                const int col = cbase + n * 16;
                const float val = v[r];
                if constexpr (EPI == 0) {
                    const int which = col >> 10, cc = col & 1023;
                    const float* bp = (which == 0) ? b0 : (which == 1) ? b1 : b2;
                    const int bb = row >> 11, t = row & 2047;
                    const int nh = cc >> 6, hh = cc & 63;
                    const float bv2 = val + bp[cc];
                    if (which == 0)        // Q, pre-scaled by H^-0.5 * log2(e)
                        o0[(((size_t)(bb * 16 + nh) * 2048 + t) << 6) + hh] =
                            (bf16)(bv2 * 0.18033688011112042f);
                    else if (which == 1)   // K
                        o1[(((size_t)(bb * 16 + nh) * 2048 + t) << 6) + hh] =
                            (bf16)bv2;
                    else                   // V transposed: [Z][64][2048]
                        o2[(((size_t)(bb * 16 + nh) * 64 + hh) << 11) + t] =
                            (bf16)bv2;
                } else if constexpr (EPI == 1) {
                    of[(size_t)row * N + col] =
                        val + b0[col] + res[(size_t)row * N + col];
                } else {
                    const float xg = val + b0[col];
                    const float z2 = 1.5957691216f * (xg + 0.044715f * xg * xg * xg);
                    o0[(size_t)row * N + col] = (bf16)(xg / (1.f + __expf(-z2)));
                }
            }
        }
    }
}

// ---------------------------------------------------------------------------
// Flash attention, swapped-QK^T + in-register softmax + K/V LDS dbuf
// (single barrier per tile). exp2 domain: Q pre-scaled by 0.125*log2e.
// Grid: T/64 x B*N. 4 waves; wave owns 16 q rows.
// ---------------------------------------------------------------------------
__global__ __launch_bounds__(256) void attn_kernel(
    const bf16* __restrict__ q, const bf16* __restrict__ k,
    const bf16* __restrict__ vt, bf16* __restrict__ enc)
{
    __shared__ bf16 Qs[64][72];
    __shared__ bf16 Ks[2][64][72];
    __shared__ bf16 Vs[2][64][72];    // [h][s]

    const int tid = threadIdx.x, wave = tid >> 6, lane = tid & 63;
    const int lr = lane & 15, lk = (lane >> 4) * 8;
    const bool geven = ((lane >> 4) & 1) == 0;
    const int qsel = (lane >> 4) << 2;
    const int id = xcd_swz(blockIdx.y * gridDim.x + blockIdx.x, 1024);
    const int qt = id % 32, z = id / 32;
    const bf16* qb = q + ((size_t)z * 2048 + qt * 64) * 64;
    const bf16* kb = k + (size_t)z * 2048 * 64;
    const bf16* vb = vt + (size_t)z * 64 * 2048;

    const int sr = tid >> 3, so = (tid & 7) * 8;

    for (int c = tid; c < 512; c += 256) {
        const int r = c >> 3, o = (c & 7) * 8;
        *(bf16x8*)&Qs[r][o] = *(const bf16x8*)&qb[r * 64 + o];
    }

    bf16x8 kr0, kr1, vr0, vr1;
    auto load_tile = [&](int st) {
        kr0 = *(const bf16x8*)&kb[(size_t)(st * 64 + sr) * 64 + so];
        kr1 = *(const bf16x8*)&kb[(size_t)(st * 64 + sr + 32) * 64 + so];
        vr0 = *(const bf16x8*)&vb[(size_t)sr * 2048 + st * 64 + so];
        vr1 = *(const bf16x8*)&vb[(size_t)(sr + 32) * 2048 + st * 64 + so];
    };
    auto write_tile = [&](int b) {
        *(bf16x8*)&Ks[b][sr][so]      = kr0;
        *(bf16x8*)&Ks[b][sr + 32][so] = kr1;
        *(bf16x8*)&Vs[b][sr][so]      = vr0;
        *(bf16x8*)&Vs[b][sr + 32][so] = vr1;
    };

    load_tile(0);
    write_tile(0);
    __syncthreads();
    const bf16x8 aq0 = *(const bf16x8*)&Qs[wave * 16 + lr][lk];
    const bf16x8 aq1 = *(const bf16x8*)&Qs[wave * 16 + lr][32 + lk];

    float m_run = -1e30f, l_run = 0.f;
    f32x4 accO[4] = {};
    int cur = 0;

    for (int kt = 0; kt < 32; ++kt) {
        if (kt < 31) load_tile(kt + 1);   // reg prefetch under compute

        f32x4 p4[4] = {};
        __builtin_amdgcn_s_setprio(1);
        #pragma unroll
        for (int j = 0; j < 4; ++j) {
            p4[j] = MFMA16(*(const bf16x8*)&Ks[cur][j * 16 + lr][lk],      aq0, p4[j], 0, 0, 0);
            p4[j] = MFMA16(*(const bf16x8*)&Ks[cur][j * 16 + lr][32 + lk], aq1, p4[j], 0, 0, 0);
        }
        __builtin_amdgcn_s_setprio(0);

        float pmax = p4[0][0];
        #pragma unroll
        for (int j = 0; j < 4; ++j)
            #pragma unroll
            for (int r = 0; r < 4; ++r) pmax = fmaxf(pmax, p4[j][r]);
        pmax = fmaxf(pmax, __shfl_xor(pmax, 16));
        pmax = fmaxf(pmax, __shfl_xor(pmax, 32));

        // defer-max (log2 domain, THR = 8*log2e)
        if (__any(pmax - m_run > 11.54f)) {
            const float mnew = fmaxf(m_run, pmax);
            const float fac = fexp2(m_run - mnew);
            m_run = mnew;
            l_run *= fac;
            float facq[4];
            #pragma unroll
            for (int r = 0; r < 4; ++r) facq[r] = __shfl(fac, qsel + r);
            #pragma unroll
            for (int nh = 0; nh < 4; ++nh)
                #pragma unroll
                for (int r = 0; r < 4; ++r) accO[nh][r] *= facq[r];
        }

        float rsum = 0.f;
        #pragma unroll
        for (int j = 0; j < 4; ++j)
            #pragma unroll
            for (int r = 0; r < 4; ++r) {
                const float e = fexp2(p4[j][r] - m_run);
                p4[j][r] = e;
                rsum += e;
            }
        rsum += __shfl_xor(rsum, 16);
        rsum += __shfl_xor(rsum, 32);
        l_run += rsum;

        unsigned w[4][2];
        #pragma unroll
        for (int j = 0; j < 4; ++j) {
            w[j][0] = pk2(p4[j][0], p4[j][1]);
            w[j][1] = pk2(p4[j][2], p4[j][3]);
        }
        union FW { unsigned u[4]; bf16x8 v; } f0, f1;
        #pragma unroll
        for (int f = 0; f < 2; ++f) {
            FW& fw = f ? f1 : f0;
            #pragma unroll
            for (int rr = 0; rr < 2; ++rr) {
                unsigned X = w[2 * f][rr], Y = w[2 * f + 1][rr];
                pl32swap(X, Y);
                const unsigned SX = (unsigned)__shfl_xor((int)X, 16);
                const unsigned SY = (unsigned)__shfl_xor((int)Y, 16);
                fw.u[rr]     = geven ? X  : SY;
                fw.u[2 + rr] = geven ? SX : Y;
            }
        }

        __builtin_amdgcn_s_setprio(1);
        #pragma unroll
        for (int nh = 0; nh < 4; ++nh) {
            accO[nh] = MFMA16(f0.v, *(const bf16x8*)&Vs[cur][nh * 16 + lr][lk],      accO[nh], 0, 0, 0);
            accO[nh] = MFMA16(f1.v, *(const bf16x8*)&Vs[cur][nh * 16 + lr][32 + lk], accO[nh], 0, 0, 0);
        }
        __builtin_amdgcn_s_setprio(0);

        if (kt < 31) write_tile(cur ^ 1);   // other buffer: no race with readers
        __syncthreads();                    // writes visible; everyone done with cur
        cur ^= 1;
    }

    float lq[4];
    #pragma unroll
    for (int r = 0; r < 4; ++r) lq[r] = __shfl(l_run, qsel + r);

    const int bb = z >> 4, nn = z & 15;
    #pragma unroll
    for (int nh = 0; nh < 4; ++nh)
        #pragma unroll
        for (int r = 0; r < 4; ++r) {
            const int t = qt * 64 + wave * 16 + qsel + r;
            const int hh = nh * 16 + lr;
            enc[((size_t)(bb * 2048 + t)) * 1024 + nn * 64 + hh] =
                (bf16)(accO[nh][r] / lq[r]);
        }
}

// ---------------------------------------------------------------------------
extern "C" void kernel_launch(void* const* d_in, const int* in_sizes, int n_in,
                              void* d_out, int out_size, void* d_ws, size_t ws_size,
                              hipStream_t stream) {
    const float* x    = (const float*)d_in[0];
    const float* ln0s = (const float*)d_in[1];
    const float* ln0b = (const float*)d_in[2];
    const float* ln1s = (const float*)d_in[3];
    const float* ln1b = (const float*)d_in[4];
    const float* wq   = (const float*)d_in[5];
    const float* bq   = (const float*)d_in[6];
    const float* wk   = (const float*)d_in[7];
    const float* bk   = (const float*)d_in[8];
    const float* wv   = (const float*)d_in[9];
    const float* bv   = (const float*)d_in[10];
    const float* wo   = (const float*)d_in[11];
    const float* bo   = (const float*)d_in[12];
    const float* w0   = (const float*)d_in[13];
    const float* b0   = (const float*)d_in[14];
    const float* w1   = (const float*)d_in[15];
    const float* b1   = (const float*)d_in[16];
    float* out = (float*)d_out;

    // workspace layout
    char* p = (char*)d_ws;
    bf16* Wqkv = (bf16*)p; p += (size_t)3072 * 1024 * 2;
    bf16* Wot  = (bf16*)p; p += (size_t)1024 * 1024 * 2;
    bf16* W0t  = (bf16*)p; p += (size_t)4096 * 1024 * 2;
    bf16* W1t  = (bf16*)p; p += (size_t)1024 * 4096 * 2;
    bf16* y0   = (bf16*)p; p += (size_t)4096 * 1024 * 2;
    bf16* qbuf = (bf16*)p; p += (size_t)4096 * 1024 * 2;
    bf16* kbuf = (bf16*)p; p += (size_t)4096 * 1024 * 2;
    bf16* vtb  = (bf16*)p; p += (size_t)4096 * 1024 * 2;
    bf16* enc  = (bf16*)p; p += (size_t)4096 * 1024 * 2;
    float* x1  = (float*)p; p += (size_t)4096 * 1024 * 4;
    bf16* y1   = (bf16*)p; p += (size_t)4096 * 1024 * 2;
    bf16* h    = (bf16*)p; p += (size_t)4096 * 4096 * 2;

    const dim3 tb(32, 8);
    // weights -> bf16, transposed to [N][K]
    transpose_cast<<<dim3(32, 32), tb, 0, stream>>>(wq, Wqkv, 1024, 1024);
    transpose_cast<<<dim3(32, 32), tb, 0, stream>>>(wk, Wqkv + (size_t)1024 * 1024, 1024, 1024);
    transpose_cast<<<dim3(32, 32), tb, 0, stream>>>(wv, Wqkv + (size_t)2048 * 1024, 1024, 1024);
    transpose_cast<<<dim3(32, 32), tb, 0, stream>>>(wo, Wot, 1024, 1024);
    transpose_cast<<<dim3(128, 32), tb, 0, stream>>>(w0, W0t, 1024, 4096);
    transpose_cast<<<dim3(32, 128), tb, 0, stream>>>(w1, W1t, 4096, 1024);

    ln_kernel<<<4096, 256, 0, stream>>>(x, ln0s, ln0b, y0);

    // fused QKV projection: [4096,1024] @ [1024,3072]; V written transposed
    gemm_kernel<0, 128, 128, 4><<<dim3(24, 32), 256, 0, stream>>>(
        y0, Wqkv, 4096, 3072, 1024, bq, bk, bv, nullptr, qbuf, kbuf, vtb, nullptr);

    attn_kernel<<<dim3(32, 32), 256, 0, stream>>>(qbuf, kbuf, vtb, enc);

    // out projection + residual -> x1 (fp32)
    gemm_kernel<1, 128, 128, 4><<<dim3(8, 32), 256, 0, stream>>>(
        enc, Wot, 4096, 1024, 1024, bo, nullptr, nullptr, x, nullptr, nullptr, nullptr, x1);

    ln_kernel<<<4096, 256, 0, stream>>>(x1, ln1s, ln1b, y1);

    // MLP up + GELU -> h (bf16): 256x256 tile, 8 waves, grid 256 = 1/CU
    gemm_kernel<2, 256, 256, 8><<<dim3(16, 16), 512, 0, stream>>>(
        y1, W0t, 4096, 4096, 1024, b0, nullptr, nullptr, nullptr, h, nullptr, nullptr, nullptr);

    // MLP down + bias + residual -> out (fp32)
    gemm_kernel<1, 128, 128, 4><<<dim3(8, 32), 256, 0, stream>>>(
        h, W1t, 4096, 1024, 4096, b1, nullptr, nullptr, x1, nullptr, nullptr, nullptr, out);
}

// Round 7
// 328.161 us; speedup vs baseline: 1.0573x; 1.0573x over previous
//
#include <hip/hip_runtime.h>
#include <cstdint>
#include <cstddef>

typedef __bf16 bf16;
typedef __attribute__((ext_vector_type(8))) __bf16 bf16x8;
typedef __attribute__((ext_vector_type(4))) __bf16 bf16x4;
typedef __attribute__((ext_vector_type(4))) float f32x4;

#define MFMA16 __builtin_amdgcn_mfma_f32_16x16x32_bf16

// async global -> LDS, 16B per lane. LDS dest is base + lane*16.
__device__ __forceinline__ void gload16(const bf16* g, bf16* l) {
    __builtin_amdgcn_global_load_lds(
        (const __attribute__((address_space(1))) uint32_t*)g,
        (__attribute__((address_space(3))) uint32_t*)l, 16, 0, 0);
}

// pack two f32 -> u32 of 2 bf16 (elem0 = lo bits)
__device__ __forceinline__ unsigned pk2(float lo, float hi) {
    union { bf16 h[2]; unsigned u; } c;
    c.h[0] = (bf16)lo; c.h[1] = (bf16)hi;
    return c.u;
}
// v_permlane32_swap_b32: a' = [a.lo | b.lo], b' = [a.hi | b.hi]
__device__ __forceinline__ void pl32swap(unsigned& a, unsigned& b) {
    asm volatile("v_permlane32_swap_b32 %0, %1" : "+v"(a), "+v"(b));
}
// raw v_exp_f32: 2^x
__device__ __forceinline__ float fexp2(float x) {
    float r;
    asm("v_exp_f32 %0, %1" : "=v"(r) : "v"(x));
    return r;
}

// bijective XCD chunk swizzle (nwg % 8 == 0)
__device__ __forceinline__ int xcd_swz(int id, int nwg) {
    return (id & 7) * (nwg >> 3) + (id >> 3);
}

// ---------------------------------------------------------------------------
// Tiled transpose + fp32->bf16 cast:  src [K][N] fp32  ->  dst [N][K] bf16
// ---------------------------------------------------------------------------
__global__ __launch_bounds__(256) void transpose_cast(
    const float* __restrict__ src, bf16* __restrict__ dst, int K, int N)
{
    __shared__ float t[32][33];
    const int n0 = blockIdx.x * 32, k0 = blockIdx.y * 32;
    const int tx = threadIdx.x, ty = threadIdx.y;
    #pragma unroll
    for (int i = ty; i < 32; i += 8)
        t[i][tx] = src[(size_t)(k0 + i) * N + n0 + tx];
    __syncthreads();
    #pragma unroll
    for (int i = ty; i < 32; i += 8)
        dst[(size_t)(n0 + i) * K + k0 + tx] = (bf16)t[tx][i];
}

// ---------------------------------------------------------------------------
// Batched bf16 transpose for V: src [Z][2048][64] -> dst [Z][64][2048]
// ---------------------------------------------------------------------------
__global__ __launch_bounds__(256) void transpose_v(
    const bf16* __restrict__ src, bf16* __restrict__ dst)
{
    __shared__ bf16 t[32][33];
    const int z = blockIdx.z;
    const int h0 = blockIdx.x * 32, s0 = blockIdx.y * 32;
    const bf16* sp = src + (size_t)z * 2048 * 64;
    bf16* dp = dst + (size_t)z * 64 * 2048;
    const int tx = threadIdx.x, ty = threadIdx.y;
    #pragma unroll
    for (int i = ty; i < 32; i += 8)
        t[i][tx] = sp[(size_t)(s0 + i) * 64 + h0 + tx];
    __syncthreads();
    #pragma unroll
    for (int i = ty; i < 32; i += 8)
        dp[(size_t)(h0 + i) * 2048 + s0 + tx] = t[tx][i];
}

// ---------------------------------------------------------------------------
// LayerNorm (D=1024) fp32 in -> bf16 out. One block (256 thr) per row.
// ---------------------------------------------------------------------------
__global__ __launch_bounds__(256) void ln_kernel(
    const float* __restrict__ x, const float* __restrict__ sc,
    const float* __restrict__ bi, bf16* __restrict__ y)
{
    const int row = blockIdx.x, tid = threadIdx.x;
    const f32x4 v = ((const f32x4*)(x + (size_t)row * 1024))[tid];
    float s  = v[0] + v[1] + v[2] + v[3];
    float s2 = v[0]*v[0] + v[1]*v[1] + v[2]*v[2] + v[3]*v[3];
    #pragma unroll
    for (int d = 1; d < 64; d <<= 1) {
        s  += __shfl_xor(s, d);
        s2 += __shfl_xor(s2, d);
    }
    __shared__ float red[8];
    if ((tid & 63) == 0) { red[tid >> 6] = s; red[4 + (tid >> 6)] = s2; }
    __syncthreads();
    s  = red[0] + red[1] + red[2] + red[3];
    s2 = red[4] + red[5] + red[6] + red[7];
    const float mu = s * (1.f / 1024.f);
    const float rstd = rsqrtf(s2 * (1.f / 1024.f) - mu * mu + 1e-6f);
    const f32x4 s4 = ((const f32x4*)sc)[tid];
    const f32x4 b4 = ((const f32x4*)bi)[tid];
    bf16x4 o;
    #pragma unroll
    for (int j = 0; j < 4; ++j)
        o[j] = (bf16)((v[j] - mu) * rstd * s4[j] + b4[j]);
    ((bf16x4*)(y + (size_t)row * 1024))[tid] = o;
}

// ---------------------------------------------------------------------------
// bf16 GEMM, 2-phase LDS dbuf, BK=64, linear LDS (R4-validated structure).
// Tile BM x BN, NW waves. Per K-step: issue next tile's global_load_lds
// FIRST, then ds_read+MFMA current (2 k-halves), then ONE __syncthreads.
// EPI 0: QKV scatter (+bias; Q pre-scaled by 0.125*log2e), [Z][T][H] x3.
// EPI 1: fp32 out = acc + bias[col] + res[row][col]
// EPI 2: bf16 out = gelu(acc + bias[col])   (sigmoid form)
// ---------------------------------------------------------------------------
template <int EPI, int BM, int BN, int NW>
__global__ __launch_bounds__(NW * 64, 2) void gemm_kernel(
    const bf16* __restrict__ A, const bf16* __restrict__ Bt,
    int M, int N, int K,
    const float* __restrict__ b0, const float* __restrict__ b1,
    const float* __restrict__ b2, const float* __restrict__ res,
    bf16* __restrict__ o0, bf16* __restrict__ o1, bf16* __restrict__ o2,
    float* __restrict__ of)
{
    constexpr int NRW = NW / 2;          // wave cols (2 or 4)
    constexpr int MR  = BM / 32;         // row frags/wave (4 or 8)
    constexpr int NR  = BN / 16 / NRW;   // col frags/wave (4)
    __shared__ bf16 As[2][BM * 64];
    __shared__ bf16 Bs[2][BN * 64];

    const int tid = threadIdx.x;
    const int wave = tid >> 6, lane = tid & 63;
    const int wr = (wave / NRW) * (MR * 16), wc = (wave % NRW) * (NR * 16);
    const int lr = lane & 15, lk = (lane >> 4) * 8;

    const int nwg = gridDim.x * gridDim.y;
    const int id = xcd_swz(blockIdx.y * gridDim.x + blockIdx.x, nwg);
    const int bm = (id / gridDim.x) * BM, bn = (id % gridDim.x) * BN;

    f32x4 acc[MR][NR] = {};

    // staging: 4 calls per operand; call c covers rows [c*8*NW, c*8*NW+8*NW)
    const int srow = tid >> 3;
    const int scol = (tid & 7) * 8;
    const bf16* Ag = A  + (size_t)(bm + srow) * K + scol;
    const bf16* Bg = Bt + (size_t)(bn + srow) * K + scol;

    auto stage = [&](int buf, int k0) {
        #pragma unroll
        for (int c = 0; c < 4; ++c)
            gload16(Ag + (size_t)(c * 8 * NW) * K + k0,
                    &As[buf][(c * 8 * NW) * 64] + (size_t)tid * 8);
        #pragma unroll
        for (int c = 0; c < 4; ++c)
            gload16(Bg + (size_t)(c * 8 * NW) * K + k0,
                    &Bs[buf][(c * 8 * NW) * 64] + (size_t)tid * 8);
    };

    const int nk = K >> 6;
    stage(0, 0);
    __syncthreads();
    int cur = 0;
    for (int i = 0; i < nk; ++i) {
        if (i + 1 < nk) stage(cur ^ 1, (i + 1) << 6);   // flies under MFMA
        #pragma unroll
        for (int kh = 0; kh < 2; ++kh) {
            const int ko = kh * 32 + lk;
            bf16x8 a[MR], b[NR];
            #pragma unroll
            for (int m = 0; m < MR; ++m)
                a[m] = *(const bf16x8*)&As[cur][(wr + m * 16 + lr) * 64 + ko];
            #pragma unroll
            for (int n = 0; n < NR; ++n)
                b[n] = *(const bf16x8*)&Bs[cur][(wc + n * 16 + lr) * 64 + ko];
            #pragma unroll
            for (int m = 0; m < MR; ++m)
                #pragma unroll
                for (int n = 0; n < NR; ++n)
                    acc[m][n] = MFMA16(a[m], b[n], acc[m][n], 0, 0, 0);
        }
        __syncthreads();   // implicit vmcnt(0): prefetch landed; cur free
        cur ^= 1;
    }

    const int rbase = bm + wr + ((lane >> 4) << 2);
    const int cbase = bn + wc + lr;
    #pragma unroll
    for (int m = 0; m < MR; ++m) {
        #pragma unroll
        for (int n = 0; n < NR; ++n) {
            const f32x4 v = acc[m][n];
            #pragma unroll
            for (int r = 0; r < 4; ++r) {
                const int row = rbase + m * 16 + r;
                const int col = cbase + n * 16;
                const float val = v[r];
                if constexpr (EPI == 0) {
                    const int which = col >> 10, cc = col & 1023;
                    const float* bp = (which == 0) ? b0 : (which == 1) ? b1 : b2;
                    bf16* dp = (which == 0) ? o0 : (which == 1) ? o1 : o2;
                    // Q pre-scaled by H^-0.5 * log2(e) for exp2-domain softmax
                    const float scl = (which == 0) ? 0.18033688011112042f : 1.0f;
                    const int bb = row >> 11, t = row & 2047;
                    const int nh = cc >> 6, hh = cc & 63;
                    dp[(((size_t)(bb * 16 + nh) * 2048 + t) << 6) + hh] =
                        (bf16)((val + bp[cc]) * scl);
                } else if constexpr (EPI == 1) {
                    of[(size_t)row * N + col] =
                        val + b0[col] + res[(size_t)row * N + col];
                } else {
                    const float xg = val + b0[col];
                    const float z2 = 1.5957691216f * (xg + 0.044715f * xg * xg * xg);
                    o0[(size_t)row * N + col] = (bf16)(xg / (1.f + __expf(-z2)));
                }
            }
        }
    }
}

// ---------------------------------------------------------------------------
// Flash attention (R3-validated structure: single K/V buffer, 2 barriers per
// tile) with swapped-QK^T + in-register softmax, exp2 domain (Q pre-scaled
// by 0.125*log2e). Grid: T/64 x B*N. 4 waves; wave owns 16 q rows.
// ---------------------------------------------------------------------------
__global__ __launch_bounds__(256) void attn_kernel(
    const bf16* __restrict__ q, const bf16* __restrict__ k,
    const bf16* __restrict__ vt, bf16* __restrict__ enc)
{
    __shared__ bf16 Qs[64][72];
    __shared__ bf16 Ks[64][72];
    __shared__ bf16 Vs[64][72];       // [h][s]

    const int tid = threadIdx.x, wave = tid >> 6, lane = tid & 63;
    const int lr = lane & 15, lk = (lane >> 4) * 8;
    const bool geven = ((lane >> 4) & 1) == 0;
    const int qsel = (lane >> 4) << 2;
    const int id = xcd_swz(blockIdx.y * gridDim.x + blockIdx.x, 1024);
    const int qt = id % 32, z = id / 32;
    const bf16* qb = q + ((size_t)z * 2048 + qt * 64) * 64;
    const bf16* kb = k + (size_t)z * 2048 * 64;
    const bf16* vb = vt + (size_t)z * 64 * 2048;

    const int sr = tid >> 3, so = (tid & 7) * 8;

    for (int c = tid; c < 512; c += 256) {
        const int r = c >> 3, o = (c & 7) * 8;
        *(bf16x8*)&Qs[r][o] = *(const bf16x8*)&qb[r * 64 + o];
    }

    bf16x8 kr0, kr1, vr0, vr1;
    auto load_tile = [&](int st) {
        kr0 = *(const bf16x8*)&kb[(size_t)(st * 64 + sr) * 64 + so];
        kr1 = *(const bf16x8*)&kb[(size_t)(st * 64 + sr + 32) * 64 + so];
        vr0 = *(const bf16x8*)&vb[(size_t)sr * 2048 + st * 64 + so];
        vr1 = *(const bf16x8*)&vb[(size_t)(sr + 32) * 2048 + st * 64 + so];
    };
    auto write_tile = [&]() {
        *(bf16x8*)&Ks[sr][so]      = kr0;
        *(bf16x8*)&Ks[sr + 32][so] = kr1;
        *(bf16x8*)&Vs[sr][so]      = vr0;
        *(bf16x8*)&Vs[sr + 32][so] = vr1;
    };

    load_tile(0);
    write_tile();
    __syncthreads();
    const bf16x8 aq0 = *(const bf16x8*)&Qs[wave * 16 + lr][lk];
    const bf16x8 aq1 = *(const bf16x8*)&Qs[wave * 16 + lr][32 + lk];

    float m_run = -1e30f, l_run = 0.f;
    f32x4 accO[4] = {};

    for (int kt = 0; kt < 32; ++kt) {
        if (kt < 31) load_tile(kt + 1);   // reg prefetch under compute

        f32x4 p4[4] = {};
        __builtin_amdgcn_s_setprio(1);
        #pragma unroll
        for (int j = 0; j < 4; ++j) {
            p4[j] = MFMA16(*(const bf16x8*)&Ks[j * 16 + lr][lk],      aq0, p4[j], 0, 0, 0);
            p4[j] = MFMA16(*(const bf16x8*)&Ks[j * 16 + lr][32 + lk], aq1, p4[j], 0, 0, 0);
        }
        __builtin_amdgcn_s_setprio(0);

        float pmax = p4[0][0];
        #pragma unroll
        for (int j = 0; j < 4; ++j)
            #pragma unroll
            for (int r = 0; r < 4; ++r) pmax = fmaxf(pmax, p4[j][r]);
        pmax = fmaxf(pmax, __shfl_xor(pmax, 16));
        pmax = fmaxf(pmax, __shfl_xor(pmax, 32));

        // defer-max (log2 domain, THR = 8*log2e)
        if (__any(pmax - m_run > 11.54f)) {
            const float mnew = fmaxf(m_run, pmax);
            const float fac = fexp2(m_run - mnew);
            m_run = mnew;
            l_run *= fac;
            float facq[4];
            #pragma unroll
            for (int r = 0; r < 4; ++r) facq[r] = __shfl(fac, qsel + r);
            #pragma unroll
            for (int nh = 0; nh < 4; ++nh)
                #pragma unroll
                for (int r = 0; r < 4; ++r) accO[nh][r] *= facq[r];
        }

        float rsum = 0.f;
        #pragma unroll
        for (int j = 0; j < 4; ++j)
            #pragma unroll
            for (int r = 0; r < 4; ++r) {
                const float e = fexp2(p4[j][r] - m_run);
                p4[j][r] = e;
                rsum += e;
            }
        rsum += __shfl_xor(rsum, 16);
        rsum += __shfl_xor(rsum, 32);
        l_run += rsum;

        unsigned w[4][2];
        #pragma unroll
        for (int j = 0; j < 4; ++j) {
            w[j][0] = pk2(p4[j][0], p4[j][1]);
            w[j][1] = pk2(p4[j][2], p4[j][3]);
        }
        union FW { unsigned u[4]; bf16x8 v; } f0, f1;
        #pragma unroll
        for (int f = 0; f < 2; ++f) {
            FW& fw = f ? f1 : f0;
            #pragma unroll
            for (int rr = 0; rr < 2; ++rr) {
                unsigned X = w[2 * f][rr], Y = w[2 * f + 1][rr];
                pl32swap(X, Y);
                const unsigned SX = (unsigned)__shfl_xor((int)X, 16);
                const unsigned SY = (unsigned)__shfl_xor((int)Y, 16);
                fw.u[rr]     = geven ? X  : SY;
                fw.u[2 + rr] = geven ? SX : Y;
            }
        }

        __builtin_amdgcn_s_setprio(1);
        #pragma unroll
        for (int nh = 0; nh < 4; ++nh) {
            accO[nh] = MFMA16(f0.v, *(const bf16x8*)&Vs[nh * 16 + lr][lk],      accO[nh], 0, 0, 0);
            accO[nh] = MFMA16(f1.v, *(const bf16x8*)&Vs[nh * 16 + lr][32 + lk], accO[nh], 0, 0, 0);
        }
        __builtin_amdgcn_s_setprio(0);

        __syncthreads();
        if (kt < 31) write_tile();
        __syncthreads();
    }

    float lq[4];
    #pragma unroll
    for (int r = 0; r < 4; ++r) lq[r] = __shfl(l_run, qsel + r);

    const int bb = z >> 4, nn = z & 15;
    #pragma unroll
    for (int nh = 0; nh < 4; ++nh)
        #pragma unroll
        for (int r = 0; r < 4; ++r) {
            const int t = qt * 64 + wave * 16 + qsel + r;
            const int hh = nh * 16 + lr;
            enc[((size_t)(bb * 2048 + t)) * 1024 + nn * 64 + hh] =
                (bf16)(accO[nh][r] / lq[r]);
        }
}

// ---------------------------------------------------------------------------
extern "C" void kernel_launch(void* const* d_in, const int* in_sizes, int n_in,
                              void* d_out, int out_size, void* d_ws, size_t ws_size,
                              hipStream_t stream) {
    const float* x    = (const float*)d_in[0];
    const float* ln0s = (const float*)d_in[1];
    const float* ln0b = (const float*)d_in[2];
    const float* ln1s = (const float*)d_in[3];
    const float* ln1b = (const float*)d_in[4];
    const float* wq   = (const float*)d_in[5];
    const float* bq   = (const float*)d_in[6];
    const float* wk   = (const float*)d_in[7];
    const float* bk   = (const float*)d_in[8];
    const float* wv   = (const float*)d_in[9];
    const float* bv   = (const float*)d_in[10];
    const float* wo   = (const float*)d_in[11];
    const float* bo   = (const float*)d_in[12];
    const float* w0   = (const float*)d_in[13];
    const float* b0   = (const float*)d_in[14];
    const float* w1   = (const float*)d_in[15];
    const float* b1   = (const float*)d_in[16];
    float* out = (float*)d_out;

    // workspace layout (128 MiB)
    char* p = (char*)d_ws;
    bf16* Wqkv = (bf16*)p; p += (size_t)3072 * 1024 * 2;
    bf16* Wot  = (bf16*)p; p += (size_t)1024 * 1024 * 2;
    bf16* W0t  = (bf16*)p; p += (size_t)4096 * 1024 * 2;
    bf16* W1t  = (bf16*)p; p += (size_t)1024 * 4096 * 2;
    bf16* y0   = (bf16*)p; p += (size_t)4096 * 1024 * 2;
    bf16* qbuf = (bf16*)p; p += (size_t)4096 * 1024 * 2;
    bf16* kbuf = (bf16*)p; p += (size_t)4096 * 1024 * 2;
    bf16* vbuf = (bf16*)p; p += (size_t)4096 * 1024 * 2;
    bf16* vtb  = (bf16*)p; p += (size_t)4096 * 1024 * 2;
    bf16* enc  = (bf16*)p; p += (size_t)4096 * 1024 * 2;
    float* x1  = (float*)p; p += (size_t)4096 * 1024 * 4;
    bf16* y1   = (bf16*)p; p += (size_t)4096 * 1024 * 2;
    bf16* h    = (bf16*)p; p += (size_t)4096 * 4096 * 2;

    const dim3 tb(32, 8);
    // weights -> bf16, transposed to [N][K]
    transpose_cast<<<dim3(32, 32), tb, 0, stream>>>(wq, Wqkv, 1024, 1024);
    transpose_cast<<<dim3(32, 32), tb, 0, stream>>>(wk, Wqkv + (size_t)1024 * 1024, 1024, 1024);
    transpose_cast<<<dim3(32, 32), tb, 0, stream>>>(wv, Wqkv + (size_t)2048 * 1024, 1024, 1024);
    transpose_cast<<<dim3(32, 32), tb, 0, stream>>>(wo, Wot, 1024, 1024);
    transpose_cast<<<dim3(128, 32), tb, 0, stream>>>(w0, W0t, 1024, 4096);
    transpose_cast<<<dim3(32, 128), tb, 0, stream>>>(w1, W1t, 4096, 1024);

    ln_kernel<<<4096, 256, 0, stream>>>(x, ln0s, ln0b, y0);

    // fused QKV projection: [4096,1024] @ [1024,3072]
    gemm_kernel<0, 128, 128, 4><<<dim3(24, 32), 256, 0, stream>>>(
        y0, Wqkv, 4096, 3072, 1024, bq, bk, bv, nullptr, qbuf, kbuf, vbuf, nullptr);

    transpose_v<<<dim3(2, 64, 32), tb, 0, stream>>>(vbuf, vtb);

    attn_kernel<<<dim3(32, 32), 256, 0, stream>>>(qbuf, kbuf, vtb, enc);

    // out projection + residual -> x1 (fp32)
    gemm_kernel<1, 128, 128, 4><<<dim3(8, 32), 256, 0, stream>>>(
        enc, Wot, 4096, 1024, 1024, bo, nullptr, nullptr, x, nullptr, nullptr, nullptr, x1);

    ln_kernel<<<4096, 256, 0, stream>>>(x1, ln1s, ln1b, y1);

    // MLP up + GELU -> h (bf16): 256x256 tile, 8 waves, grid 256 = 1/CU
    gemm_kernel<2, 256, 256, 8><<<dim3(16, 16), 512, 0, stream>>>(
        y1, W0t, 4096, 4096, 1024, b0, nullptr, nullptr, nullptr, h, nullptr, nullptr, nullptr);

    // MLP down + bias + residual -> out (fp32)
    gemm_kernel<1, 128, 128, 4><<<dim3(8, 32), 256, 0, stream>>>(
        h, W1t, 4096, 1024, 4096, b1, nullptr, nullptr, x1, nullptr, nullptr, nullptr, out);
}

// Round 8
// 299.922 us; speedup vs baseline: 1.1568x; 1.0942x over previous
//
#include <hip/hip_runtime.h>
#include <cstdint>
#include <cstddef>

typedef __bf16 bf16;
typedef __attribute__((ext_vector_type(8))) __bf16 bf16x8;
typedef __attribute__((ext_vector_type(4))) __bf16 bf16x4;
typedef __attribute__((ext_vector_type(4))) float f32x4;

#define MFMA16 __builtin_amdgcn_mfma_f32_16x16x32_bf16

// async global -> LDS, 16B per lane. LDS dest is base + lane*16.
__device__ __forceinline__ void gload16(const bf16* g, bf16* l) {
    __builtin_amdgcn_global_load_lds(
        (const __attribute__((address_space(1))) uint32_t*)g,
        (__attribute__((address_space(3))) uint32_t*)l, 16, 0, 0);
}

// pack two f32 -> u32 of 2 bf16 (elem0 = lo bits)
__device__ __forceinline__ unsigned pk2(float lo, float hi) {
    union { bf16 h[2]; unsigned u; } c;
    c.h[0] = (bf16)lo; c.h[1] = (bf16)hi;
    return c.u;
}
// v_permlane32_swap_b32: a' = [a.lo | b.lo], b' = [a.hi | b.hi]
__device__ __forceinline__ void pl32swap(unsigned& a, unsigned& b) {
    asm volatile("v_permlane32_swap_b32 %0, %1" : "+v"(a), "+v"(b));
}
// raw v_exp_f32: 2^x
__device__ __forceinline__ float fexp2(float x) {
    float r;
    asm("v_exp_f32 %0, %1" : "=v"(r) : "v"(x));
    return r;
}

// bijective XCD chunk swizzle (nwg % 8 == 0)
__device__ __forceinline__ int xcd_swz(int id, int nwg) {
    return (id & 7) * (nwg >> 3) + (id >> 3);
}

#define SBAR()  __builtin_amdgcn_s_barrier()
#define SCHED() __builtin_amdgcn_sched_barrier(0)

// ---------------------------------------------------------------------------
// Tiled transpose + fp32->bf16 cast:  src [K][N] fp32  ->  dst [N][K] bf16
// ---------------------------------------------------------------------------
__global__ __launch_bounds__(256) void transpose_cast(
    const float* __restrict__ src, bf16* __restrict__ dst, int K, int N)
{
    __shared__ float t[32][33];
    const int n0 = blockIdx.x * 32, k0 = blockIdx.y * 32;
    const int tx = threadIdx.x, ty = threadIdx.y;
    #pragma unroll
    for (int i = ty; i < 32; i += 8)
        t[i][tx] = src[(size_t)(k0 + i) * N + n0 + tx];
    __syncthreads();
    #pragma unroll
    for (int i = ty; i < 32; i += 8)
        dst[(size_t)(n0 + i) * K + k0 + tx] = (bf16)t[tx][i];
}

// ---------------------------------------------------------------------------
// Batched bf16 transpose for V: src [Z][2048][64] -> dst [Z][64][2048]
// ---------------------------------------------------------------------------
__global__ __launch_bounds__(256) void transpose_v(
    const bf16* __restrict__ src, bf16* __restrict__ dst)
{
    __shared__ bf16 t[32][33];
    const int z = blockIdx.z;
    const int h0 = blockIdx.x * 32, s0 = blockIdx.y * 32;
    const bf16* sp = src + (size_t)z * 2048 * 64;
    bf16* dp = dst + (size_t)z * 64 * 2048;
    const int tx = threadIdx.x, ty = threadIdx.y;
    #pragma unroll
    for (int i = ty; i < 32; i += 8)
        t[i][tx] = sp[(size_t)(s0 + i) * 64 + h0 + tx];
    __syncthreads();
    #pragma unroll
    for (int i = ty; i < 32; i += 8)
        dp[(size_t)(h0 + i) * 2048 + s0 + tx] = t[tx][i];
}

// ---------------------------------------------------------------------------
// LayerNorm (D=1024) fp32 in -> bf16 out. One block (256 thr) per row.
// ---------------------------------------------------------------------------
__global__ __launch_bounds__(256) void ln_kernel(
    const float* __restrict__ x, const float* __restrict__ sc,
    const float* __restrict__ bi, bf16* __restrict__ y)
{
    const int row = blockIdx.x, tid = threadIdx.x;
    const f32x4 v = ((const f32x4*)(x + (size_t)row * 1024))[tid];
    float s  = v[0] + v[1] + v[2] + v[3];
    float s2 = v[0]*v[0] + v[1]*v[1] + v[2]*v[2] + v[3]*v[3];
    #pragma unroll
    for (int d = 1; d < 64; d <<= 1) {
        s  += __shfl_xor(s, d);
        s2 += __shfl_xor(s2, d);
    }
    __shared__ float red[8];
    if ((tid & 63) == 0) { red[tid >> 6] = s; red[4 + (tid >> 6)] = s2; }
    __syncthreads();
    s  = red[0] + red[1] + red[2] + red[3];
    s2 = red[4] + red[5] + red[6] + red[7];
    const float mu = s * (1.f / 1024.f);
    const float rstd = rsqrtf(s2 * (1.f / 1024.f) - mu * mu + 1e-6f);
    const f32x4 s4 = ((const f32x4*)sc)[tid];
    const f32x4 b4 = ((const f32x4*)bi)[tid];
    bf16x4 o;
    #pragma unroll
    for (int j = 0; j < 4; ++j)
        o[j] = (bf16)((v[j] - mu) * rstd * s4[j] + b4[j]);
    ((bf16x4*)(y + (size_t)row * 1024))[tid] = o;
}

// ---------------------------------------------------------------------------
// bf16 GEMM, dbuf + COUNTED vmcnt (no drain-0 in loop) + st_16x32 swizzle.
// Tile BM x BN, BK=64, NW waves. Per iter:
//   stage(buf^1, t+1) -> vmcnt(8) [prev tile landed] -> s_barrier ->
//   ds_read(swz) + MFMA -> lgkmcnt(0) -> s_barrier [buf free].
// Swizzle (rule #21 both-sides): linear DMA dest; source col ^= bit; read
// offset ^= bit  (byte ^= ((byte>>9)&1)<<5, m201 st_16x32).
// EPI 0: QKV scatter (+bias; Q pre-scaled by 0.125*log2e), [Z][T][H] x3.
// EPI 1: fp32 out = acc + bias[col] + res[row][col]
// EPI 2: bf16 out = gelu(acc + bias[col])   (sigmoid form)
// ---------------------------------------------------------------------------
template <int EPI, int BM, int BN, int NW>
__global__ __launch_bounds__(NW * 64, 2) void gemm_kernel(
    const bf16* __restrict__ A, const bf16* __restrict__ Bt,
    int M, int N, int K,
    const float* __restrict__ b0, const float* __restrict__ b1,
    const float* __restrict__ b2, const float* __restrict__ res,
    bf16* __restrict__ o0, bf16* __restrict__ o1, bf16* __restrict__ o2,
    float* __restrict__ of)
{
    constexpr int NRW = NW / 2;          // wave cols (2 or 4)
    constexpr int MR  = BM / 32;         // row frags/wave (4 or 8)
    constexpr int NR  = BN / 16 / NRW;   // col frags/wave (4)
    __shared__ bf16 As[2][BM * 64];
    __shared__ bf16 Bs[2][BN * 64];

    const int tid = threadIdx.x;
    const int wave = tid >> 6, lane = tid & 63;
    const int wr = (wave / NRW) * (MR * 16), wc = (wave % NRW) * (NR * 16);
    const int lr = lane & 15, lg = lane >> 4;

    const int nwg = gridDim.x * gridDim.y;
    const int id = xcd_swz(blockIdx.y * gridDim.x + blockIdx.x, nwg);
    const int bm = (id / gridDim.x) * BM, bn = (id % gridDim.x) * BN;

    f32x4 acc[MR][NR] = {};

    // staging: 4 calls/operand; call c covers rows [c*8*NW, c*8*NW+8*NW)
    // source col pre-swizzled: elem ((tid&7)*8) ^ (((row>>2)&1)<<4);
    // (row>>2)&1 == (tid>>5)&1 for every call since rows/call % 8 == 0.
    const int srow = tid >> 3;
    const int scol = ((tid & 7) * 8) ^ (((tid >> 5) & 1) << 4);
    const bf16* Ag = A  + (size_t)(bm + srow) * K + scol;
    const bf16* Bg = Bt + (size_t)(bn + srow) * K + scol;

    auto stage = [&](int buf, int k0) {
        #pragma unroll
        for (int c = 0; c < 4; ++c)
            gload16(Ag + (size_t)(c * 8 * NW) * K + k0,
                    &As[buf][(c * 8 * NW) * 64] + (size_t)tid * 8);
        #pragma unroll
        for (int c = 0; c < 4; ++c)
            gload16(Bg + (size_t)(c * 8 * NW) * K + k0,
                    &Bs[buf][(c * 8 * NW) * 64] + (size_t)tid * 8);
    };

    // read offsets, swizzled: ko = (kh*32 + lg*8) ^ (((lr>>2)&1)<<4)
    const int rsw = ((lane >> 2) & 1) << 4;
    const int ko0 = (lg * 8) ^ rsw;          // kh = 0
    const int ko1 = (32 + lg * 8) ^ rsw;     // kh = 1

    const int nk = K >> 6;
    stage(0, 0);
    __syncthreads();                          // prologue: full drain once
    int cur = 0;
    for (int i = 0; i < nk; ++i) {
        if (i + 1 < nk) {
            stage(cur ^ 1, (i + 1) << 6);     // 8 loads fly under this iter
            SCHED();
            asm volatile("s_waitcnt vmcnt(8)" ::: "memory");  // prev tile in
        } else {
            asm volatile("s_waitcnt vmcnt(0)" ::: "memory");
        }
        SCHED();
        SBAR();                               // all waves gated -> tile i live
        SCHED();
        #pragma unroll
        for (int kh = 0; kh < 2; ++kh) {
            const int ko = kh ? ko1 : ko0;
            bf16x8 a[MR], b[NR];
            #pragma unroll
            for (int m = 0; m < MR; ++m)
                a[m] = *(const bf16x8*)&As[cur][(wr + m * 16 + lr) * 64 + ko];
            #pragma unroll
            for (int n = 0; n < NR; ++n)
                b[n] = *(const bf16x8*)&Bs[cur][(wc + n * 16 + lr) * 64 + ko];
            #pragma unroll
            for (int m = 0; m < MR; ++m)
                #pragma unroll
                for (int n = 0; n < NR; ++n)
                    acc[m][n] = MFMA16(a[m], b[n], acc[m][n], 0, 0, 0);
        }
        SCHED();
        asm volatile("s_waitcnt lgkmcnt(0)" ::: "memory");    // reads done
        SCHED();
        SBAR();                               // buf[cur] free for overwrite
        SCHED();
        cur ^= 1;
    }

    const int rbase = bm + wr + (lg << 2);
    const int cbase = bn + wc + lr;
    #pragma unroll
    for (int m = 0; m < MR; ++m) {
        #pragma unroll
        for (int n = 0; n < NR; ++n) {
            const f32x4 v = acc[m][n];
            #pragma unroll
            for (int r = 0; r < 4; ++r) {
                const int row = rbase + m * 16 + r;
                const int col = cbase + n * 16;
                const float val = v[r];
                if constexpr (EPI == 0) {
                    const int which = col >> 10, cc = col & 1023;
                    const float* bp = (which == 0) ? b0 : (which == 1) ? b1 : b2;
                    bf16* dp = (which == 0) ? o0 : (which == 1) ? o1 : o2;
                    // Q pre-scaled by H^-0.5 * log2(e) for exp2-domain softmax
                    const float scl = (which == 0) ? 0.18033688011112042f : 1.0f;
                    const int bb = row >> 11, t = row & 2047;
                    const int nh = cc >> 6, hh = cc & 63;
                    dp[(((size_t)(bb * 16 + nh) * 2048 + t) << 6) + hh] =
                        (bf16)((val + bp[cc]) * scl);
                } else if constexpr (EPI == 1) {
                    of[(size_t)row * N + col] =
                        val + b0[col] + res[(size_t)row * N + col];
                } else {
                    const float xg = val + b0[col];
                    const float z2 = 1.5957691216f * (xg + 0.044715f * xg * xg * xg);
                    o0[(size_t)row * N + col] = (bf16)(xg / (1.f + __expf(-z2)));
                }
            }
        }
    }
}

// ---------------------------------------------------------------------------
// Flash attention (R7-validated, unchanged): single K/V buffer, 2 barriers
// per tile, swapped-QK^T + in-register softmax, exp2 domain.
// ---------------------------------------------------------------------------
__global__ __launch_bounds__(256) void attn_kernel(
    const bf16* __restrict__ q, const bf16* __restrict__ k,
    const bf16* __restrict__ vt, bf16* __restrict__ enc)
{
    __shared__ bf16 Qs[64][72];
    __shared__ bf16 Ks[64][72];
    __shared__ bf16 Vs[64][72];       // [h][s]

    const int tid = threadIdx.x, wave = tid >> 6, lane = tid & 63;
    const int lr = lane & 15, lk = (lane >> 4) * 8;
    const bool geven = ((lane >> 4) & 1) == 0;
    const int qsel = (lane >> 4) << 2;
    const int id = xcd_swz(blockIdx.y * gridDim.x + blockIdx.x, 1024);
    const int qt = id % 32, z = id / 32;
    const bf16* qb = q + ((size_t)z * 2048 + qt * 64) * 64;
    const bf16* kb = k + (size_t)z * 2048 * 64;
    const bf16* vb = vt + (size_t)z * 64 * 2048;

    const int sr = tid >> 3, so = (tid & 7) * 8;

    for (int c = tid; c < 512; c += 256) {
        const int r = c >> 3, o = (c & 7) * 8;
        *(bf16x8*)&Qs[r][o] = *(const bf16x8*)&qb[r * 64 + o];
    }

    bf16x8 kr0, kr1, vr0, vr1;
    auto load_tile = [&](int st) {
        kr0 = *(const bf16x8*)&kb[(size_t)(st * 64 + sr) * 64 + so];
        kr1 = *(const bf16x8*)&kb[(size_t)(st * 64 + sr + 32) * 64 + so];
        vr0 = *(const bf16x8*)&vb[(size_t)sr * 2048 + st * 64 + so];
        vr1 = *(const bf16x8*)&vb[(size_t)(sr + 32) * 2048 + st * 64 + so];
    };
    auto write_tile = [&]() {
        *(bf16x8*)&Ks[sr][so]      = kr0;
        *(bf16x8*)&Ks[sr + 32][so] = kr1;
        *(bf16x8*)&Vs[sr][so]      = vr0;
        *(bf16x8*)&Vs[sr + 32][so] = vr1;
    };

    load_tile(0);
    write_tile();
    __syncthreads();
    const bf16x8 aq0 = *(const bf16x8*)&Qs[wave * 16 + lr][lk];
    const bf16x8 aq1 = *(const bf16x8*)&Qs[wave * 16 + lr][32 + lk];

    float m_run = -1e30f, l_run = 0.f;
    f32x4 accO[4] = {};

    for (int kt = 0; kt < 32; ++kt) {
        if (kt < 31) load_tile(kt + 1);   // reg prefetch under compute

        f32x4 p4[4] = {};
        __builtin_amdgcn_s_setprio(1);
        #pragma unroll
        for (int j = 0; j < 4; ++j) {
            p4[j] = MFMA16(*(const bf16x8*)&Ks[j * 16 + lr][lk],      aq0, p4[j], 0, 0, 0);
            p4[j] = MFMA16(*(const bf16x8*)&Ks[j * 16 + lr][32 + lk], aq1, p4[j], 0, 0, 0);
        }
        __builtin_amdgcn_s_setprio(0);

        float pmax = p4[0][0];
        #pragma unroll
        for (int j = 0; j < 4; ++j)
            #pragma unroll
            for (int r = 0; r < 4; ++r) pmax = fmaxf(pmax, p4[j][r]);
        pmax = fmaxf(pmax, __shfl_xor(pmax, 16));
        pmax = fmaxf(pmax, __shfl_xor(pmax, 32));

        // defer-max (log2 domain, THR = 8*log2e)
        if (__any(pmax - m_run > 11.54f)) {
            const float mnew = fmaxf(m_run, pmax);
            const float fac = fexp2(m_run - mnew);
            m_run = mnew;
            l_run *= fac;
            float facq[4];
            #pragma unroll
            for (int r = 0; r < 4; ++r) facq[r] = __shfl(fac, qsel + r);
            #pragma unroll
            for (int nh = 0; nh < 4; ++nh)
                #pragma unroll
                for (int r = 0; r < 4; ++r) accO[nh][r] *= facq[r];
        }

        float rsum = 0.f;
        #pragma unroll
        for (int j = 0; j < 4; ++j)
            #pragma unroll
            for (int r = 0; r < 4; ++r) {
                const float e = fexp2(p4[j][r] - m_run);
                p4[j][r] = e;
                rsum += e;
            }
        rsum += __shfl_xor(rsum, 16);
        rsum += __shfl_xor(rsum, 32);
        l_run += rsum;

        unsigned w[4][2];
        #pragma unroll
        for (int j = 0; j < 4; ++j) {
            w[j][0] = pk2(p4[j][0], p4[j][1]);
            w[j][1] = pk2(p4[j][2], p4[j][3]);
        }
        union FW { unsigned u[4]; bf16x8 v; } f0, f1;
        #pragma unroll
        for (int f = 0; f < 2; ++f) {
            FW& fw = f ? f1 : f0;
            #pragma unroll
            for (int rr = 0; rr < 2; ++rr) {
                unsigned X = w[2 * f][rr], Y = w[2 * f + 1][rr];
                pl32swap(X, Y);
                const unsigned SX = (unsigned)__shfl_xor((int)X, 16);
                const unsigned SY = (unsigned)__shfl_xor((int)Y, 16);
                fw.u[rr]     = geven ? X  : SY;
                fw.u[2 + rr] = geven ? SX : Y;
            }
        }

        __builtin_amdgcn_s_setprio(1);
        #pragma unroll
        for (int nh = 0; nh < 4; ++nh) {
            accO[nh] = MFMA16(f0.v, *(const bf16x8*)&Vs[nh * 16 + lr][lk],      accO[nh], 0, 0, 0);
            accO[nh] = MFMA16(f1.v, *(const bf16x8*)&Vs[nh * 16 + lr][32 + lk], accO[nh], 0, 0, 0);
        }
        __builtin_amdgcn_s_setprio(0);

        __syncthreads();
        if (kt < 31) write_tile();
        __syncthreads();
    }

    float lq[4];
    #pragma unroll
    for (int r = 0; r < 4; ++r) lq[r] = __shfl(l_run, qsel + r);

    const int bb = z >> 4, nn = z & 15;
    #pragma unroll
    for (int nh = 0; nh < 4; ++nh)
        #pragma unroll
        for (int r = 0; r < 4; ++r) {
            const int t = qt * 64 + wave * 16 + qsel + r;
            const int hh = nh * 16 + lr;
            enc[((size_t)(bb * 2048 + t)) * 1024 + nn * 64 + hh] =
                (bf16)(accO[nh][r] / lq[r]);
        }
}

// ---------------------------------------------------------------------------
extern "C" void kernel_launch(void* const* d_in, const int* in_sizes, int n_in,
                              void* d_out, int out_size, void* d_ws, size_t ws_size,
                              hipStream_t stream) {
    const float* x    = (const float*)d_in[0];
    const float* ln0s = (const float*)d_in[1];
    const float* ln0b = (const float*)d_in[2];
    const float* ln1s = (const float*)d_in[3];
    const float* ln1b = (const float*)d_in[4];
    const float* wq   = (const float*)d_in[5];
    const float* bq   = (const float*)d_in[6];
    const float* wk   = (const float*)d_in[7];
    const float* bk   = (const float*)d_in[8];
    const float* wv   = (const float*)d_in[9];
    const float* bv   = (const float*)d_in[10];
    const float* wo   = (const float*)d_in[11];
    const float* bo   = (const float*)d_in[12];
    const float* w0   = (const float*)d_in[13];
    const float* b0   = (const float*)d_in[14];
    const float* w1   = (const float*)d_in[15];
    const float* b1   = (const float*)d_in[16];
    float* out = (float*)d_out;

    // workspace layout (128 MiB)
    char* p = (char*)d_ws;
    bf16* Wqkv = (bf16*)p; p += (size_t)3072 * 1024 * 2;
    bf16* Wot  = (bf16*)p; p += (size_t)1024 * 1024 * 2;
    bf16* W0t  = (bf16*)p; p += (size_t)4096 * 1024 * 2;
    bf16* W1t  = (bf16*)p; p += (size_t)1024 * 4096 * 2;
    bf16* y0   = (bf16*)p; p += (size_t)4096 * 1024 * 2;
    bf16* qbuf = (bf16*)p; p += (size_t)4096 * 1024 * 2;
    bf16* kbuf = (bf16*)p; p += (size_t)4096 * 1024 * 2;
    bf16* vbuf = (bf16*)p; p += (size_t)4096 * 1024 * 2;
    bf16* vtb  = (bf16*)p; p += (size_t)4096 * 1024 * 2;
    bf16* enc  = (bf16*)p; p += (size_t)4096 * 1024 * 2;
    float* x1  = (float*)p; p += (size_t)4096 * 1024 * 4;
    bf16* y1   = (bf16*)p; p += (size_t)4096 * 1024 * 2;
    bf16* h    = (bf16*)p; p += (size_t)4096 * 4096 * 2;

    const dim3 tb(32, 8);
    // weights -> bf16, transposed to [N][K]
    transpose_cast<<<dim3(32, 32), tb, 0, stream>>>(wq, Wqkv, 1024, 1024);
    transpose_cast<<<dim3(32, 32), tb, 0, stream>>>(wk, Wqkv + (size_t)1024 * 1024, 1024, 1024);
    transpose_cast<<<dim3(32, 32), tb, 0, stream>>>(wv, Wqkv + (size_t)2048 * 1024, 1024, 1024);
    transpose_cast<<<dim3(32, 32), tb, 0, stream>>>(wo, Wot, 1024, 1024);
    transpose_cast<<<dim3(128, 32), tb, 0, stream>>>(w0, W0t, 1024, 4096);
    transpose_cast<<<dim3(32, 128), tb, 0, stream>>>(w1, W1t, 4096, 1024);

    ln_kernel<<<4096, 256, 0, stream>>>(x, ln0s, ln0b, y0);

    // fused QKV projection: [4096,1024] @ [1024,3072]
    gemm_kernel<0, 128, 128, 4><<<dim3(24, 32), 256, 0, stream>>>(
        y0, Wqkv, 4096, 3072, 1024, bq, bk, bv, nullptr, qbuf, kbuf, vbuf, nullptr);

    transpose_v<<<dim3(2, 64, 32), tb, 0, stream>>>(vbuf, vtb);

    attn_kernel<<<dim3(32, 32), 256, 0, stream>>>(qbuf, kbuf, vtb, enc);

    // out projection + residual -> x1 (fp32)
    gemm_kernel<1, 128, 128, 4><<<dim3(8, 32), 256, 0, stream>>>(
        enc, Wot, 4096, 1024, 1024, bo, nullptr, nullptr, x, nullptr, nullptr, nullptr, x1);

    ln_kernel<<<4096, 256, 0, stream>>>(x1, ln1s, ln1b, y1);

    // MLP up + GELU -> h (bf16): 256x256 tile, 8 waves, grid 256 = 1/CU
    gemm_kernel<2, 256, 256, 8><<<dim3(16, 16), 512, 0, stream>>>(
        y1, W0t, 4096, 4096, 1024, b0, nullptr, nullptr, nullptr, h, nullptr, nullptr, nullptr);

    // MLP down + bias + residual -> out (fp32)
    gemm_kernel<1, 128, 128, 4><<<dim3(8, 32), 256, 0, stream>>>(
        h, W1t, 4096, 1024, 4096, b1, nullptr, nullptr, x1, nullptr, nullptr, nullptr, out);
}

// Round 9
// 287.059 us; speedup vs baseline: 1.2087x; 1.0448x over previous
//
#include <hip/hip_runtime.h>
#include <cstdint>
#include <cstddef>

typedef __bf16 bf16;
typedef __attribute__((ext_vector_type(8))) __bf16 bf16x8;
typedef __attribute__((ext_vector_type(4))) __bf16 bf16x4;
typedef __attribute__((ext_vector_type(4))) float f32x4;

#define MFMA16 __builtin_amdgcn_mfma_f32_16x16x32_bf16

// async global -> LDS, 16B per lane. LDS dest is base + lane*16.
__device__ __forceinline__ void gload16(const bf16* g, bf16* l) {
    __builtin_amdgcn_global_load_lds(
        (const __attribute__((address_space(1))) uint32_t*)g,
        (__attribute__((address_space(3))) uint32_t*)l, 16, 0, 0);
}

// pack two f32 -> u32 of 2 bf16 (elem0 = lo bits)
__device__ __forceinline__ unsigned pk2(float lo, float hi) {
    union { bf16 h[2]; unsigned u; } c;
    c.h[0] = (bf16)lo; c.h[1] = (bf16)hi;
    return c.u;
}
// v_permlane32_swap_b32: a' = [a.lo | b.lo], b' = [a.hi | b.hi]
__device__ __forceinline__ void pl32swap(unsigned& a, unsigned& b) {
    asm volatile("v_permlane32_swap_b32 %0, %1" : "+v"(a), "+v"(b));
}
// raw v_exp_f32: 2^x
__device__ __forceinline__ float fexp2(float x) {
    float r;
    asm("v_exp_f32 %0, %1" : "=v"(r) : "v"(x));
    return r;
}

// bijective XCD chunk swizzle (nwg % 8 == 0)
__device__ __forceinline__ int xcd_swz(int id, int nwg) {
    return (id & 7) * (nwg >> 3) + (id >> 3);
}

#define SBAR()  __builtin_amdgcn_s_barrier()
#define SCHED() __builtin_amdgcn_sched_barrier(0)

// ---------------------------------------------------------------------------
// Tiled transpose + fp32->bf16 cast:  src [K][N] fp32  ->  dst [N][K] bf16
// ---------------------------------------------------------------------------
__global__ __launch_bounds__(256) void transpose_cast(
    const float* __restrict__ src, bf16* __restrict__ dst, int K, int N)
{
    __shared__ float t[32][33];
    const int n0 = blockIdx.x * 32, k0 = blockIdx.y * 32;
    const int tx = threadIdx.x, ty = threadIdx.y;
    #pragma unroll
    for (int i = ty; i < 32; i += 8)
        t[i][tx] = src[(size_t)(k0 + i) * N + n0 + tx];
    __syncthreads();
    #pragma unroll
    for (int i = ty; i < 32; i += 8)
        dst[(size_t)(n0 + i) * K + k0 + tx] = (bf16)t[tx][i];
}

// ---------------------------------------------------------------------------
// Batched bf16 transpose for V: src [Z][2048][64] -> dst [Z][64][2048]
// ---------------------------------------------------------------------------
__global__ __launch_bounds__(256) void transpose_v(
    const bf16* __restrict__ src, bf16* __restrict__ dst)
{
    __shared__ bf16 t[32][33];
    const int z = blockIdx.z;
    const int h0 = blockIdx.x * 32, s0 = blockIdx.y * 32;
    const bf16* sp = src + (size_t)z * 2048 * 64;
    bf16* dp = dst + (size_t)z * 64 * 2048;
    const int tx = threadIdx.x, ty = threadIdx.y;
    #pragma unroll
    for (int i = ty; i < 32; i += 8)
        t[i][tx] = sp[(size_t)(s0 + i) * 64 + h0 + tx];
    __syncthreads();
    #pragma unroll
    for (int i = ty; i < 32; i += 8)
        dp[(size_t)(h0 + i) * 2048 + s0 + tx] = t[tx][i];
}

// ---------------------------------------------------------------------------
// LayerNorm (D=1024) fp32 in -> bf16 out. One block (256 thr) per row.
// ---------------------------------------------------------------------------
__global__ __launch_bounds__(256) void ln_kernel(
    const float* __restrict__ x, const float* __restrict__ sc,
    const float* __restrict__ bi, bf16* __restrict__ y)
{
    const int row = blockIdx.x, tid = threadIdx.x;
    const f32x4 v = ((const f32x4*)(x + (size_t)row * 1024))[tid];
    float s  = v[0] + v[1] + v[2] + v[3];
    float s2 = v[0]*v[0] + v[1]*v[1] + v[2]*v[2] + v[3]*v[3];
    #pragma unroll
    for (int d = 1; d < 64; d <<= 1) {
        s  += __shfl_xor(s, d);
        s2 += __shfl_xor(s2, d);
    }
    __shared__ float red[8];
    if ((tid & 63) == 0) { red[tid >> 6] = s; red[4 + (tid >> 6)] = s2; }
    __syncthreads();
    s  = red[0] + red[1] + red[2] + red[3];
    s2 = red[4] + red[5] + red[6] + red[7];
    const float mu = s * (1.f / 1024.f);
    const float rstd = rsqrtf(s2 * (1.f / 1024.f) - mu * mu + 1e-6f);
    const f32x4 s4 = ((const f32x4*)sc)[tid];
    const f32x4 b4 = ((const f32x4*)bi)[tid];
    bf16x4 o;
    #pragma unroll
    for (int j = 0; j < 4; ++j)
        o[j] = (bf16)((v[j] - mu) * rstd * s4[j] + b4[j]);
    ((bf16x4*)(y + (size_t)row * 1024))[tid] = o;
}

// ---------------------------------------------------------------------------
// bf16 GEMM, dbuf + COUNTED vmcnt + st_16x32-style swizzle (R8-validated).
// Tile BM x BN (BN may be BM or BM/2), BK=64, NW waves. Per iter:
//   stage(buf^1, i+1) -> vmcnt(NLOADS) [prev tile landed] -> s_barrier ->
//   ds_read(swz) + MFMA -> lgkmcnt(0) -> s_barrier [buf free].
// EPI 0: QKV scatter (+bias; Q pre-scaled by 0.125*log2e), [Z][T][H] x3.
// EPI 1: fp32 out = acc + bias[col] + res[row][col]
// EPI 2: bf16 out = gelu(acc + bias[col])   (sigmoid form)
// ---------------------------------------------------------------------------
template <int EPI, int BM, int BN, int NW>
__global__ __launch_bounds__(NW * 64, 2) void gemm_kernel(
    const bf16* __restrict__ A, const bf16* __restrict__ Bt,
    int M, int N, int K,
    const float* __restrict__ b0, const float* __restrict__ b1,
    const float* __restrict__ b2, const float* __restrict__ res,
    bf16* __restrict__ o0, bf16* __restrict__ o1, bf16* __restrict__ o2,
    float* __restrict__ of)
{
    constexpr int NRW    = NW / 2;          // wave cols
    constexpr int MR     = BM / 32;         // row frags/wave
    constexpr int NR     = BN / 16 / NRW;   // col frags/wave
    constexpr int ACALLS = BM / (8 * NW);   // stage calls for A
    constexpr int BCALLS = BN / (8 * NW);   // stage calls for B
    constexpr int NLOADS = ACALLS + BCALLS; // gload16 per stage per wave
    static_assert(NLOADS == 8 || NLOADS == 6, "vmcnt literal");
    __shared__ bf16 As[2][BM * 64];
    __shared__ bf16 Bs[2][BN * 64];

    const int tid = threadIdx.x;
    const int wave = tid >> 6, lane = tid & 63;
    const int wr = (wave / NRW) * (MR * 16), wc = (wave % NRW) * (NR * 16);
    const int lr = lane & 15, lg = lane >> 4;

    const int nwg = gridDim.x * gridDim.y;
    const int id = xcd_swz(blockIdx.y * gridDim.x + blockIdx.x, nwg);
    const int bm = (id / gridDim.x) * BM, bn = (id % gridDim.x) * BN;

    f32x4 acc[MR][NR] = {};

    // staging: call c covers rows [c*8*NW, (c+1)*8*NW)
    // source col pre-swizzled: elem ((tid&7)*8) ^ (((row>>2)&1)<<4);
    // (row>>2)&1 == (tid>>5)&1 for every call (rows/call % 8 == 0).
    const int srow = tid >> 3;
    const int scol = ((tid & 7) * 8) ^ (((tid >> 5) & 1) << 4);
    const bf16* Ag = A  + (size_t)(bm + srow) * K + scol;
    const bf16* Bg = Bt + (size_t)(bn + srow) * K + scol;

    auto stage = [&](int buf, int k0) {
        #pragma unroll
        for (int c = 0; c < ACALLS; ++c)
            gload16(Ag + (size_t)(c * 8 * NW) * K + k0,
                    &As[buf][(c * 8 * NW) * 64] + (size_t)tid * 8);
        #pragma unroll
        for (int c = 0; c < BCALLS; ++c)
            gload16(Bg + (size_t)(c * 8 * NW) * K + k0,
                    &Bs[buf][(c * 8 * NW) * 64] + (size_t)tid * 8);
    };

    // read offsets, swizzled: ko = (kh*32 + lg*8) ^ (((lr>>2)&1)<<4)
    const int rsw = ((lane >> 2) & 1) << 4;
    const int ko0 = (lg * 8) ^ rsw;          // kh = 0
    const int ko1 = (32 + lg * 8) ^ rsw;     // kh = 1

    const int nk = K >> 6;
    stage(0, 0);
    __syncthreads();                          // prologue: full drain once
    int cur = 0;
    for (int i = 0; i < nk; ++i) {
        if (i + 1 < nk) {
            stage(cur ^ 1, (i + 1) << 6);     // loads fly under this iter
            SCHED();
            if constexpr (NLOADS == 8)
                asm volatile("s_waitcnt vmcnt(8)" ::: "memory");
            else
                asm volatile("s_waitcnt vmcnt(6)" ::: "memory");
        } else {
            asm volatile("s_waitcnt vmcnt(0)" ::: "memory");
        }
        SCHED();
        SBAR();                               // all waves gated -> tile i live
        SCHED();
        #pragma unroll
        for (int kh = 0; kh < 2; ++kh) {
            const int ko = kh ? ko1 : ko0;
            bf16x8 a[MR], b[NR];
            #pragma unroll
            for (int m = 0; m < MR; ++m)
                a[m] = *(const bf16x8*)&As[cur][(wr + m * 16 + lr) * 64 + ko];
            #pragma unroll
            for (int n = 0; n < NR; ++n)
                b[n] = *(const bf16x8*)&Bs[cur][(wc + n * 16 + lr) * 64 + ko];
            #pragma unroll
            for (int m = 0; m < MR; ++m)
                #pragma unroll
                for (int n = 0; n < NR; ++n)
                    acc[m][n] = MFMA16(a[m], b[n], acc[m][n], 0, 0, 0);
        }
        SCHED();
        asm volatile("s_waitcnt lgkmcnt(0)" ::: "memory");    // reads done
        SCHED();
        SBAR();                               // buf[cur] free for overwrite
        SCHED();
        cur ^= 1;
    }

    const int rbase = bm + wr + (lg << 2);
    const int cbase = bn + wc + lr;
    #pragma unroll
    for (int m = 0; m < MR; ++m) {
        #pragma unroll
        for (int n = 0; n < NR; ++n) {
            const f32x4 v = acc[m][n];
            #pragma unroll
            for (int r = 0; r < 4; ++r) {
                const int row = rbase + m * 16 + r;
                const int col = cbase + n * 16;
                const float val = v[r];
                if constexpr (EPI == 0) {
                    const int which = col >> 10, cc = col & 1023;
                    const float* bp = (which == 0) ? b0 : (which == 1) ? b1 : b2;
                    bf16* dp = (which == 0) ? o0 : (which == 1) ? o1 : o2;
                    // Q pre-scaled by H^-0.5 * log2(e) for exp2-domain softmax
                    const float scl = (which == 0) ? 0.18033688011112042f : 1.0f;
                    const int bb = row >> 11, t = row & 2047;
                    const int nh = cc >> 6, hh = cc & 63;
                    dp[(((size_t)(bb * 16 + nh) * 2048 + t) << 6) + hh] =
                        (bf16)((val + bp[cc]) * scl);
                } else if constexpr (EPI == 1) {
                    of[(size_t)row * N + col] =
                        val + b0[col] + res[(size_t)row * N + col];
                } else {
                    const float xg = val + b0[col];
                    const float z2 = 1.5957691216f * (xg + 0.044715f * xg * xg * xg);
                    o0[(size_t)row * N + col] = (bf16)(xg / (1.f + __expf(-z2)));
                }
            }
        }
    }
}

// ---------------------------------------------------------------------------
// Flash attention (R7/R8-validated, unchanged): single K/V buffer, 2 barriers
// per tile, swapped-QK^T + in-register softmax, exp2 domain.
// ---------------------------------------------------------------------------
__global__ __launch_bounds__(256) void attn_kernel(
    const bf16* __restrict__ q, const bf16* __restrict__ k,
    const bf16* __restrict__ vt, bf16* __restrict__ enc)
{
    __shared__ bf16 Qs[64][72];
    __shared__ bf16 Ks[64][72];
    __shared__ bf16 Vs[64][72];       // [h][s]

    const int tid = threadIdx.x, wave = tid >> 6, lane = tid & 63;
    const int lr = lane & 15, lk = (lane >> 4) * 8;
    const bool geven = ((lane >> 4) & 1) == 0;
    const int qsel = (lane >> 4) << 2;
    const int id = xcd_swz(blockIdx.y * gridDim.x + blockIdx.x, 1024);
    const int qt = id % 32, z = id / 32;
    const bf16* qb = q + ((size_t)z * 2048 + qt * 64) * 64;
    const bf16* kb = k + (size_t)z * 2048 * 64;
    const bf16* vb = vt + (size_t)z * 64 * 2048;

    const int sr = tid >> 3, so = (tid & 7) * 8;

    for (int c = tid; c < 512; c += 256) {
        const int r = c >> 3, o = (c & 7) * 8;
        *(bf16x8*)&Qs[r][o] = *(const bf16x8*)&qb[r * 64 + o];
    }

    bf16x8 kr0, kr1, vr0, vr1;
    auto load_tile = [&](int st) {
        kr0 = *(const bf16x8*)&kb[(size_t)(st * 64 + sr) * 64 + so];
        kr1 = *(const bf16x8*)&kb[(size_t)(st * 64 + sr + 32) * 64 + so];
        vr0 = *(const bf16x8*)&vb[(size_t)sr * 2048 + st * 64 + so];
        vr1 = *(const bf16x8*)&vb[(size_t)(sr + 32) * 2048 + st * 64 + so];
    };
    auto write_tile = [&]() {
        *(bf16x8*)&Ks[sr][so]      = kr0;
        *(bf16x8*)&Ks[sr + 32][so] = kr1;
        *(bf16x8*)&Vs[sr][so]      = vr0;
        *(bf16x8*)&Vs[sr + 32][so] = vr1;
    };

    load_tile(0);
    write_tile();
    __syncthreads();
    const bf16x8 aq0 = *(const bf16x8*)&Qs[wave * 16 + lr][lk];
    const bf16x8 aq1 = *(const bf16x8*)&Qs[wave * 16 + lr][32 + lk];

    float m_run = -1e30f, l_run = 0.f;
    f32x4 accO[4] = {};

    for (int kt = 0; kt < 32; ++kt) {
        if (kt < 31) load_tile(kt + 1);   // reg prefetch under compute

        f32x4 p4[4] = {};
        __builtin_amdgcn_s_setprio(1);
        #pragma unroll
        for (int j = 0; j < 4; ++j) {
            p4[j] = MFMA16(*(const bf16x8*)&Ks[j * 16 + lr][lk],      aq0, p4[j], 0, 0, 0);
            p4[j] = MFMA16(*(const bf16x8*)&Ks[j * 16 + lr][32 + lk], aq1, p4[j], 0, 0, 0);
        }
        __builtin_amdgcn_s_setprio(0);

        float pmax = p4[0][0];
        #pragma unroll
        for (int j = 0; j < 4; ++j)
            #pragma unroll
            for (int r = 0; r < 4; ++r) pmax = fmaxf(pmax, p4[j][r]);
        pmax = fmaxf(pmax, __shfl_xor(pmax, 16));
        pmax = fmaxf(pmax, __shfl_xor(pmax, 32));

        // defer-max (log2 domain, THR = 8*log2e)
        if (__any(pmax - m_run > 11.54f)) {
            const float mnew = fmaxf(m_run, pmax);
            const float fac = fexp2(m_run - mnew);
            m_run = mnew;
            l_run *= fac;
            float facq[4];
            #pragma unroll
            for (int r = 0; r < 4; ++r) facq[r] = __shfl(fac, qsel + r);
            #pragma unroll
            for (int nh = 0; nh < 4; ++nh)
                #pragma unroll
                for (int r = 0; r < 4; ++r) accO[nh][r] *= facq[r];
        }

        float rsum = 0.f;
        #pragma unroll
        for (int j = 0; j < 4; ++j)
            #pragma unroll
            for (int r = 0; r < 4; ++r) {
                const float e = fexp2(p4[j][r] - m_run);
                p4[j][r] = e;
                rsum += e;
            }
        rsum += __shfl_xor(rsum, 16);
        rsum += __shfl_xor(rsum, 32);
        l_run += rsum;

        unsigned w[4][2];
        #pragma unroll
        for (int j = 0; j < 4; ++j) {
            w[j][0] = pk2(p4[j][0], p4[j][1]);
            w[j][1] = pk2(p4[j][2], p4[j][3]);
        }
        union FW { unsigned u[4]; bf16x8 v; } f0, f1;
        #pragma unroll
        for (int f = 0; f < 2; ++f) {
            FW& fw = f ? f1 : f0;
            #pragma unroll
            for (int rr = 0; rr < 2; ++rr) {
                unsigned X = w[2 * f][rr], Y = w[2 * f + 1][rr];
                pl32swap(X, Y);
                const unsigned SX = (unsigned)__shfl_xor((int)X, 16);
                const unsigned SY = (unsigned)__shfl_xor((int)Y, 16);
                fw.u[rr]     = geven ? X  : SY;
                fw.u[2 + rr] = geven ? SX : Y;
            }
        }

        __builtin_amdgcn_s_setprio(1);
        #pragma unroll
        for (int nh = 0; nh < 4; ++nh) {
            accO[nh] = MFMA16(f0.v, *(const bf16x8*)&Vs[nh * 16 + lr][lk],      accO[nh], 0, 0, 0);
            accO[nh] = MFMA16(f1.v, *(const bf16x8*)&Vs[nh * 16 + lr][32 + lk], accO[nh], 0, 0, 0);
        }
        __builtin_amdgcn_s_setprio(0);

        __syncthreads();
        if (kt < 31) write_tile();
        __syncthreads();
    }

    float lq[4];
    #pragma unroll
    for (int r = 0; r < 4; ++r) lq[r] = __shfl(l_run, qsel + r);

    const int bb = z >> 4, nn = z & 15;
    #pragma unroll
    for (int nh = 0; nh < 4; ++nh)
        #pragma unroll
        for (int r = 0; r < 4; ++r) {
            const int t = qt * 64 + wave * 16 + qsel + r;
            const int hh = nh * 16 + lr;
            enc[((size_t)(bb * 2048 + t)) * 1024 + nn * 64 + hh] =
                (bf16)(accO[nh][r] / lq[r]);
        }
}

// ---------------------------------------------------------------------------
extern "C" void kernel_launch(void* const* d_in, const int* in_sizes, int n_in,
                              void* d_out, int out_size, void* d_ws, size_t ws_size,
                              hipStream_t stream) {
    const float* x    = (const float*)d_in[0];
    const float* ln0s = (const float*)d_in[1];
    const float* ln0b = (const float*)d_in[2];
    const float* ln1s = (const float*)d_in[3];
    const float* ln1b = (const float*)d_in[4];
    const float* wq   = (const float*)d_in[5];
    const float* bq   = (const float*)d_in[6];
    const float* wk   = (const float*)d_in[7];
    const float* bk   = (const float*)d_in[8];
    const float* wv   = (const float*)d_in[9];
    const float* bv   = (const float*)d_in[10];
    const float* wo   = (const float*)d_in[11];
    const float* bo   = (const float*)d_in[12];
    const float* w0   = (const float*)d_in[13];
    const float* b0   = (const float*)d_in[14];
    const float* w1   = (const float*)d_in[15];
    const float* b1   = (const float*)d_in[16];
    float* out = (float*)d_out;

    // workspace layout (128 MiB)
    char* p = (char*)d_ws;
    bf16* Wqkv = (bf16*)p; p += (size_t)3072 * 1024 * 2;
    bf16* Wot  = (bf16*)p; p += (size_t)1024 * 1024 * 2;
    bf16* W0t  = (bf16*)p; p += (size_t)4096 * 1024 * 2;
    bf16* W1t  = (bf16*)p; p += (size_t)1024 * 4096 * 2;
    bf16* y0   = (bf16*)p; p += (size_t)4096 * 1024 * 2;
    bf16* qbuf = (bf16*)p; p += (size_t)4096 * 1024 * 2;
    bf16* kbuf = (bf16*)p; p += (size_t)4096 * 1024 * 2;
    bf16* vbuf = (bf16*)p; p += (size_t)4096 * 1024 * 2;
    bf16* vtb  = (bf16*)p; p += (size_t)4096 * 1024 * 2;
    bf16* enc  = (bf16*)p; p += (size_t)4096 * 1024 * 2;
    float* x1  = (float*)p; p += (size_t)4096 * 1024 * 4;
    bf16* y1   = (bf16*)p; p += (size_t)4096 * 1024 * 2;
    bf16* h    = (bf16*)p; p += (size_t)4096 * 4096 * 2;

    const dim3 tb(32, 8);
    // weights -> bf16, transposed to [N][K]
    transpose_cast<<<dim3(32, 32), tb, 0, stream>>>(wq, Wqkv, 1024, 1024);
    transpose_cast<<<dim3(32, 32), tb, 0, stream>>>(wk, Wqkv + (size_t)1024 * 1024, 1024, 1024);
    transpose_cast<<<dim3(32, 32), tb, 0, stream>>>(wv, Wqkv + (size_t)2048 * 1024, 1024, 1024);
    transpose_cast<<<dim3(32, 32), tb, 0, stream>>>(wo, Wot, 1024, 1024);
    transpose_cast<<<dim3(128, 32), tb, 0, stream>>>(w0, W0t, 1024, 4096);
    transpose_cast<<<dim3(32, 128), tb, 0, stream>>>(w1, W1t, 4096, 1024);

    ln_kernel<<<4096, 256, 0, stream>>>(x, ln0s, ln0b, y0);

    // fused QKV projection: [4096,1024] @ [1024,3072]
    gemm_kernel<0, 128, 128, 4><<<dim3(24, 32), 256, 0, stream>>>(
        y0, Wqkv, 4096, 3072, 1024, bq, bk, bv, nullptr, qbuf, kbuf, vbuf, nullptr);

    transpose_v<<<dim3(2, 64, 32), tb, 0, stream>>>(vbuf, vtb);

    attn_kernel<<<dim3(32, 32), 256, 0, stream>>>(qbuf, kbuf, vtb, enc);

    // out projection + residual -> x1 (fp32): 128x64 tile, 512 wg = 2/CU
    gemm_kernel<1, 128, 64, 4><<<dim3(16, 32), 256, 0, stream>>>(
        enc, Wot, 4096, 1024, 1024, bo, nullptr, nullptr, x, nullptr, nullptr, nullptr, x1);

    ln_kernel<<<4096, 256, 0, stream>>>(x1, ln1s, ln1b, y1);

    // MLP up + GELU -> h (bf16): 128x128 tile, 1024 wg = 2 blocks/CU resident
    gemm_kernel<2, 128, 128, 4><<<dim3(32, 32), 256, 0, stream>>>(
        y1, W0t, 4096, 4096, 1024, b0, nullptr, nullptr, nullptr, h, nullptr, nullptr, nullptr);

    // MLP down + bias + residual -> out (fp32): 128x64 tile, 512 wg = 2/CU
    gemm_kernel<1, 128, 64, 4><<<dim3(16, 32), 256, 0, stream>>>(
        h, W1t, 4096, 1024, 4096, b1, nullptr, nullptr, x1, nullptr, nullptr, nullptr, out);
}

// Round 10
// 279.279 us; speedup vs baseline: 1.2423x; 1.0279x over previous
//
#include <hip/hip_runtime.h>
#include <cstdint>
#include <cstddef>

typedef __bf16 bf16;
typedef __attribute__((ext_vector_type(8))) __bf16 bf16x8;
typedef __attribute__((ext_vector_type(4))) __bf16 bf16x4;
typedef __attribute__((ext_vector_type(4))) float f32x4;

#define MFMA16 __builtin_amdgcn_mfma_f32_16x16x32_bf16

// async global -> LDS, 16B per lane. LDS dest is base + lane*16.
__device__ __forceinline__ void gload16(const bf16* g, bf16* l) {
    __builtin_amdgcn_global_load_lds(
        (const __attribute__((address_space(1))) uint32_t*)g,
        (__attribute__((address_space(3))) uint32_t*)l, 16, 0, 0);
}

// pack two f32 -> u32 of 2 bf16 (elem0 = lo bits)
__device__ __forceinline__ unsigned pk2(float lo, float hi) {
    union { bf16 h[2]; unsigned u; } c;
    c.h[0] = (bf16)lo; c.h[1] = (bf16)hi;
    return c.u;
}
// raw v_exp_f32: 2^x
__device__ __forceinline__ float fexp2(float x) {
    float r;
    asm("v_exp_f32 %0, %1" : "=v"(r) : "v"(x));
    return r;
}
// v_max3_f32 (T17)
__device__ __forceinline__ float fmax3(float a, float b, float c) {
    float r;
    asm("v_max3_f32 %0, %1, %2, %3" : "=v"(r) : "v"(a), "v"(b), "v"(c));
    return r;
}

// bijective XCD chunk swizzle (nwg % 8 == 0)
__device__ __forceinline__ int xcd_swz(int id, int nwg) {
    return (id & 7) * (nwg >> 3) + (id >> 3);
}

#define SBAR()  __builtin_amdgcn_s_barrier()
#define SCHED() __builtin_amdgcn_sched_barrier(0)

// ---------------------------------------------------------------------------
// Tiled transpose + fp32->bf16 cast:  src [K][N] fp32  ->  dst [N][K] bf16
// ---------------------------------------------------------------------------
__global__ __launch_bounds__(256) void transpose_cast(
    const float* __restrict__ src, bf16* __restrict__ dst, int K, int N)
{
    __shared__ float t[32][33];
    const int n0 = blockIdx.x * 32, k0 = blockIdx.y * 32;
    const int tx = threadIdx.x, ty = threadIdx.y;
    #pragma unroll
    for (int i = ty; i < 32; i += 8)
        t[i][tx] = src[(size_t)(k0 + i) * N + n0 + tx];
    __syncthreads();
    #pragma unroll
    for (int i = ty; i < 32; i += 8)
        dst[(size_t)(n0 + i) * K + k0 + tx] = (bf16)t[tx][i];
}

// ---------------------------------------------------------------------------
// Batched bf16 transpose for V: src [Z][2048][64] -> dst [Z][64][2048]
// ---------------------------------------------------------------------------
__global__ __launch_bounds__(256) void transpose_v(
    const bf16* __restrict__ src, bf16* __restrict__ dst)
{
    __shared__ bf16 t[32][33];
    const int z = blockIdx.z;
    const int h0 = blockIdx.x * 32, s0 = blockIdx.y * 32;
    const bf16* sp = src + (size_t)z * 2048 * 64;
    bf16* dp = dst + (size_t)z * 64 * 2048;
    const int tx = threadIdx.x, ty = threadIdx.y;
    #pragma unroll
    for (int i = ty; i < 32; i += 8)
        t[i][tx] = sp[(size_t)(s0 + i) * 64 + h0 + tx];
    __syncthreads();
    #pragma unroll
    for (int i = ty; i < 32; i += 8)
        dp[(size_t)(h0 + i) * 2048 + s0 + tx] = t[tx][i];
}

// ---------------------------------------------------------------------------
// LayerNorm (D=1024) fp32 in -> bf16 out. One block (256 thr) per row.
// ---------------------------------------------------------------------------
__global__ __launch_bounds__(256) void ln_kernel(
    const float* __restrict__ x, const float* __restrict__ sc,
    const float* __restrict__ bi, bf16* __restrict__ y)
{
    const int row = blockIdx.x, tid = threadIdx.x;
    const f32x4 v = ((const f32x4*)(x + (size_t)row * 1024))[tid];
    float s  = v[0] + v[1] + v[2] + v[3];
    float s2 = v[0]*v[0] + v[1]*v[1] + v[2]*v[2] + v[3]*v[3];
    #pragma unroll
    for (int d = 1; d < 64; d <<= 1) {
        s  += __shfl_xor(s, d);
        s2 += __shfl_xor(s2, d);
    }
    __shared__ float red[8];
    if ((tid & 63) == 0) { red[tid >> 6] = s; red[4 + (tid >> 6)] = s2; }
    __syncthreads();
    s  = red[0] + red[1] + red[2] + red[3];
    s2 = red[4] + red[5] + red[6] + red[7];
    const float mu = s * (1.f / 1024.f);
    const float rstd = rsqrtf(s2 * (1.f / 1024.f) - mu * mu + 1e-6f);
    const f32x4 s4 = ((const f32x4*)sc)[tid];
    const f32x4 b4 = ((const f32x4*)bi)[tid];
    bf16x4 o;
    #pragma unroll
    for (int j = 0; j < 4; ++j)
        o[j] = (bf16)((v[j] - mu) * rstd * s4[j] + b4[j]);
    ((bf16x4*)(y + (size_t)row * 1024))[tid] = o;
}

// ---------------------------------------------------------------------------
// bf16 GEMM, dbuf + COUNTED vmcnt + st_16x32-style swizzle (R8/R9-validated,
// unchanged). Tile BM x BN, BK=64, NW waves.
// ---------------------------------------------------------------------------
template <int EPI, int BM, int BN, int NW>
__global__ __launch_bounds__(NW * 64, 2) void gemm_kernel(
    const bf16* __restrict__ A, const bf16* __restrict__ Bt,
    int M, int N, int K,
    const float* __restrict__ b0, const float* __restrict__ b1,
    const float* __restrict__ b2, const float* __restrict__ res,
    bf16* __restrict__ o0, bf16* __restrict__ o1, bf16* __restrict__ o2,
    float* __restrict__ of)
{
    constexpr int NRW    = NW / 2;          // wave cols
    constexpr int MR     = BM / 32;         // row frags/wave
    constexpr int NR     = BN / 16 / NRW;   // col frags/wave
    constexpr int ACALLS = BM / (8 * NW);   // stage calls for A
    constexpr int BCALLS = BN / (8 * NW);   // stage calls for B
    constexpr int NLOADS = ACALLS + BCALLS; // gload16 per stage per wave
    static_assert(NLOADS == 8 || NLOADS == 6, "vmcnt literal");
    __shared__ bf16 As[2][BM * 64];
    __shared__ bf16 Bs[2][BN * 64];

    const int tid = threadIdx.x;
    const int wave = tid >> 6, lane = tid & 63;
    const int wr = (wave / NRW) * (MR * 16), wc = (wave % NRW) * (NR * 16);
    const int lr = lane & 15, lg = lane >> 4;

    const int nwg = gridDim.x * gridDim.y;
    const int id = xcd_swz(blockIdx.y * gridDim.x + blockIdx.x, nwg);
    const int bm = (id / gridDim.x) * BM, bn = (id % gridDim.x) * BN;

    f32x4 acc[MR][NR] = {};

    const int srow = tid >> 3;
    const int scol = ((tid & 7) * 8) ^ (((tid >> 5) & 1) << 4);
    const bf16* Ag = A  + (size_t)(bm + srow) * K + scol;
    const bf16* Bg = Bt + (size_t)(bn + srow) * K + scol;

    auto stage = [&](int buf, int k0) {
        #pragma unroll
        for (int c = 0; c < ACALLS; ++c)
            gload16(Ag + (size_t)(c * 8 * NW) * K + k0,
                    &As[buf][(c * 8 * NW) * 64] + (size_t)tid * 8);
        #pragma unroll
        for (int c = 0; c < BCALLS; ++c)
            gload16(Bg + (size_t)(c * 8 * NW) * K + k0,
                    &Bs[buf][(c * 8 * NW) * 64] + (size_t)tid * 8);
    };

    const int rsw = ((lane >> 2) & 1) << 4;
    const int ko0 = (lg * 8) ^ rsw;          // kh = 0
    const int ko1 = (32 + lg * 8) ^ rsw;     // kh = 1

    const int nk = K >> 6;
    stage(0, 0);
    __syncthreads();                          // prologue: full drain once
    int cur = 0;
    for (int i = 0; i < nk; ++i) {
        if (i + 1 < nk) {
            stage(cur ^ 1, (i + 1) << 6);     // loads fly under this iter
            SCHED();
            if constexpr (NLOADS == 8)
                asm volatile("s_waitcnt vmcnt(8)" ::: "memory");
            else
                asm volatile("s_waitcnt vmcnt(6)" ::: "memory");
        } else {
            asm volatile("s_waitcnt vmcnt(0)" ::: "memory");
        }
        SCHED();
        SBAR();                               // all waves gated -> tile i live
        SCHED();
        #pragma unroll
        for (int kh = 0; kh < 2; ++kh) {
            const int ko = kh ? ko1 : ko0;
            bf16x8 a[MR], b[NR];
            #pragma unroll
            for (int m = 0; m < MR; ++m)
                a[m] = *(const bf16x8*)&As[cur][(wr + m * 16 + lr) * 64 + ko];
            #pragma unroll
            for (int n = 0; n < NR; ++n)
                b[n] = *(const bf16x8*)&Bs[cur][(wc + n * 16 + lr) * 64 + ko];
            #pragma unroll
            for (int m = 0; m < MR; ++m)
                #pragma unroll
                for (int n = 0; n < NR; ++n)
                    acc[m][n] = MFMA16(a[m], b[n], acc[m][n], 0, 0, 0);
        }
        SCHED();
        asm volatile("s_waitcnt lgkmcnt(0)" ::: "memory");    // reads done
        SCHED();
        SBAR();                               // buf[cur] free for overwrite
        SCHED();
        cur ^= 1;
    }

    const int rbase = bm + wr + (lg << 2);
    const int cbase = bn + wc + lr;
    #pragma unroll
    for (int m = 0; m < MR; ++m) {
        #pragma unroll
        for (int n = 0; n < NR; ++n) {
            const f32x4 v = acc[m][n];
            #pragma unroll
            for (int r = 0; r < 4; ++r) {
                const int row = rbase + m * 16 + r;
                const int col = cbase + n * 16;
                const float val = v[r];
                if constexpr (EPI == 0) {
                    const int which = col >> 10, cc = col & 1023;
                    const float* bp = (which == 0) ? b0 : (which == 1) ? b1 : b2;
                    bf16* dp = (which == 0) ? o0 : (which == 1) ? o1 : o2;
                    // Q pre-scaled by H^-0.5 * log2(e) for exp2-domain softmax
                    const float scl = (which == 0) ? 0.18033688011112042f : 1.0f;
                    const int bb = row >> 11, t = row & 2047;
                    const int nh = cc >> 6, hh = cc & 63;
                    dp[(((size_t)(bb * 16 + nh) * 2048 + t) << 6) + hh] =
                        (bf16)((val + bp[cc]) * scl);
                } else if constexpr (EPI == 1) {
                    of[(size_t)row * N + col] =
                        val + b0[col] + res[(size_t)row * N + col];
                } else {
                    const float xg = val + b0[col];
                    const float z2 = 1.5957691216f * (xg + 0.044715f * xg * xg * xg);
                    o0[(size_t)row * N + col] = (bf16)(xg / (1.f + __expf(-z2)));
                }
            }
        }
    }
}

// ---------------------------------------------------------------------------
// Flash attention, swapped-QK^T + in-register softmax + SIGMA-PERMUTED V:
// MFMA contracts over physical k-slots; we permute the k-index by
// sigma(g*8+i) = (i>>2)*16 + g*4 + (i&3) on BOTH operands. The P A-frag is
// then built from the lane's OWN p4 registers (8 pk2, zero cross-lane ops);
// the permutation is applied to V at LDS-write time (row s -> slot rho(s)).
// B-frag read addresses unchanged (b128, 2-way-free banks).
// ---------------------------------------------------------------------------
__global__ __launch_bounds__(256) void attn_kernel(
    const bf16* __restrict__ q, const bf16* __restrict__ k,
    const bf16* __restrict__ vt, bf16* __restrict__ enc)
{
    __shared__ bf16 Qs[64][72];
    __shared__ bf16 Ks[64][72];
    __shared__ bf16 Vs[64][72];       // [h][sigma-permuted s-slot]

    const int tid = threadIdx.x, wave = tid >> 6, lane = tid & 63;
    const int lr = lane & 15, lk = (lane >> 4) * 8;
    const int qsel = (lane >> 4) << 2;
    const int id = xcd_swz(blockIdx.y * gridDim.x + blockIdx.x, 1024);
    const int qt = id % 32, z = id / 32;
    const bf16* qb = q + ((size_t)z * 2048 + qt * 64) * 64;
    const bf16* kb = k + (size_t)z * 2048 * 64;
    const bf16* vb = vt + (size_t)z * 64 * 2048;

    const int sr = tid >> 3, so = (tid & 7) * 8;
    // V permuted write base: slots b0..b0+3 and b0+8..b0+11
    const int vb0 = (so & 32) + ((so >> 4) & 1) * 4 + ((so >> 3) & 1) * 16;

    for (int c = tid; c < 512; c += 256) {
        const int r = c >> 3, o = (c & 7) * 8;
        *(bf16x8*)&Qs[r][o] = *(const bf16x8*)&qb[r * 64 + o];
    }

    union V8 { bf16x8 v; bf16x4 h[2]; };
    bf16x8 kr0, kr1;
    V8 vr0, vr1;
    auto load_tile = [&](int st) {
        kr0 = *(const bf16x8*)&kb[(size_t)(st * 64 + sr) * 64 + so];
        kr1 = *(const bf16x8*)&kb[(size_t)(st * 64 + sr + 32) * 64 + so];
        vr0.v = *(const bf16x8*)&vb[(size_t)sr * 2048 + st * 64 + so];
        vr1.v = *(const bf16x8*)&vb[(size_t)(sr + 32) * 2048 + st * 64 + so];
    };
    auto write_tile = [&]() {
        *(bf16x8*)&Ks[sr][so]      = kr0;
        *(bf16x8*)&Ks[sr + 32][so] = kr1;
        *(bf16x4*)&Vs[sr][vb0]          = vr0.h[0];
        *(bf16x4*)&Vs[sr][vb0 + 8]      = vr0.h[1];
        *(bf16x4*)&Vs[sr + 32][vb0]     = vr1.h[0];
        *(bf16x4*)&Vs[sr + 32][vb0 + 8] = vr1.h[1];
    };

    load_tile(0);
    write_tile();
    __syncthreads();
    const bf16x8 aq0 = *(const bf16x8*)&Qs[wave * 16 + lr][lk];
    const bf16x8 aq1 = *(const bf16x8*)&Qs[wave * 16 + lr][32 + lk];

    float m_run = -1e30f, l_run = 0.f;
    f32x4 accO[4] = {};

    for (int kt = 0; kt < 32; ++kt) {
        if (kt < 31) load_tile(kt + 1);   // reg prefetch under compute

        f32x4 p4[4] = {};
        __builtin_amdgcn_s_setprio(1);
        #pragma unroll
        for (int j = 0; j < 4; ++j) {
            p4[j] = MFMA16(*(const bf16x8*)&Ks[j * 16 + lr][lk],      aq0, p4[j], 0, 0, 0);
            p4[j] = MFMA16(*(const bf16x8*)&Ks[j * 16 + lr][32 + lk], aq1, p4[j], 0, 0, 0);
        }
        __builtin_amdgcn_s_setprio(0);

        // row max: v_max3 chain (T17) + 2 cross-group shuffles
        float pmax = fmax3(p4[0][0], p4[0][1], p4[0][2]);
        pmax = fmax3(pmax, p4[0][3], p4[1][0]);
        pmax = fmax3(pmax, p4[1][1], p4[1][2]);
        pmax = fmax3(pmax, p4[1][3], p4[2][0]);
        pmax = fmax3(pmax, p4[2][1], p4[2][2]);
        pmax = fmax3(pmax, p4[2][3], p4[3][0]);
        pmax = fmax3(pmax, p4[3][1], p4[3][2]);
        pmax = fmaxf(pmax, p4[3][3]);
        pmax = fmaxf(pmax, __shfl_xor(pmax, 16));
        pmax = fmaxf(pmax, __shfl_xor(pmax, 32));

        // defer-max (log2 domain, THR = 8*log2e)
        if (__any(pmax - m_run > 11.54f)) {
            const float mnew = fmaxf(m_run, pmax);
            const float fac = fexp2(m_run - mnew);
            m_run = mnew;
            l_run *= fac;
            float facq[4];
            #pragma unroll
            for (int r = 0; r < 4; ++r) facq[r] = __shfl(fac, qsel + r);
            #pragma unroll
            for (int nh = 0; nh < 4; ++nh)
                #pragma unroll
                for (int r = 0; r < 4; ++r) accO[nh][r] *= facq[r];
        }

        float rsum = 0.f;
        #pragma unroll
        for (int j = 0; j < 4; ++j)
            #pragma unroll
            for (int r = 0; r < 4; ++r) {
                const float e = fexp2(p4[j][r] - m_run);
                p4[j][r] = e;
                rsum += e;
            }
        rsum += __shfl_xor(rsum, 16);
        rsum += __shfl_xor(rsum, 32);
        l_run += rsum;

        // sigma-permuted A-frags: lane's own registers, no cross-lane ops.
        // slot (g,i) holds P[q][sigma] with sigma = (i>>2)*16 + g*4 + (i&3).
        union FW { unsigned u[4]; bf16x8 v; } f0, f1;
        f0.u[0] = pk2(p4[0][0], p4[0][1]);
        f0.u[1] = pk2(p4[0][2], p4[0][3]);
        f0.u[2] = pk2(p4[1][0], p4[1][1]);
        f0.u[3] = pk2(p4[1][2], p4[1][3]);
        f1.u[0] = pk2(p4[2][0], p4[2][1]);
        f1.u[1] = pk2(p4[2][2], p4[2][3]);
        f1.u[2] = pk2(p4[3][0], p4[3][1]);
        f1.u[3] = pk2(p4[3][2], p4[3][3]);

        __builtin_amdgcn_s_setprio(1);
        #pragma unroll
        for (int nh = 0; nh < 4; ++nh) {
            accO[nh] = MFMA16(f0.v, *(const bf16x8*)&Vs[nh * 16 + lr][lk],      accO[nh], 0, 0, 0);
            accO[nh] = MFMA16(f1.v, *(const bf16x8*)&Vs[nh * 16 + lr][32 + lk], accO[nh], 0, 0, 0);
        }
        __builtin_amdgcn_s_setprio(0);

        __syncthreads();
        if (kt < 31) write_tile();
        __syncthreads();
    }

    float lq[4];
    #pragma unroll
    for (int r = 0; r < 4; ++r) lq[r] = __shfl(l_run, qsel + r);

    const int bb = z >> 4, nn = z & 15;
    #pragma unroll
    for (int nh = 0; nh < 4; ++nh)
        #pragma unroll
        for (int r = 0; r < 4; ++r) {
            const int t = qt * 64 + wave * 16 + qsel + r;
            const int hh = nh * 16 + lr;
            enc[((size_t)(bb * 2048 + t)) * 1024 + nn * 64 + hh] =
                (bf16)(accO[nh][r] / lq[r]);
        }
}

// ---------------------------------------------------------------------------
extern "C" void kernel_launch(void* const* d_in, const int* in_sizes, int n_in,
                              void* d_out, int out_size, void* d_ws, size_t ws_size,
                              hipStream_t stream) {
    const float* x    = (const float*)d_in[0];
    const float* ln0s = (const float*)d_in[1];
    const float* ln0b = (const float*)d_in[2];
    const float* ln1s = (const float*)d_in[3];
    const float* ln1b = (const float*)d_in[4];
    const float* wq   = (const float*)d_in[5];
    const float* bq   = (const float*)d_in[6];
    const float* wk   = (const float*)d_in[7];
    const float* bk   = (const float*)d_in[8];
    const float* wv   = (const float*)d_in[9];
    const float* bv   = (const float*)d_in[10];
    const float* wo   = (const float*)d_in[11];
    const float* bo   = (const float*)d_in[12];
    const float* w0   = (const float*)d_in[13];
    const float* b0   = (const float*)d_in[14];
    const float* w1   = (const float*)d_in[15];
    const float* b1   = (const float*)d_in[16];
    float* out = (float*)d_out;

    // workspace layout (128 MiB)
    char* p = (char*)d_ws;
    bf16* Wqkv = (bf16*)p; p += (size_t)3072 * 1024 * 2;
    bf16* Wot  = (bf16*)p; p += (size_t)1024 * 1024 * 2;
    bf16* W0t  = (bf16*)p; p += (size_t)4096 * 1024 * 2;
    bf16* W1t  = (bf16*)p; p += (size_t)1024 * 4096 * 2;
    bf16* y0   = (bf16*)p; p += (size_t)4096 * 1024 * 2;
    bf16* qbuf = (bf16*)p; p += (size_t)4096 * 1024 * 2;
    bf16* kbuf = (bf16*)p; p += (size_t)4096 * 1024 * 2;
    bf16* vbuf = (bf16*)p; p += (size_t)4096 * 1024 * 2;
    bf16* vtb  = (bf16*)p; p += (size_t)4096 * 1024 * 2;
    bf16* enc  = (bf16*)p; p += (size_t)4096 * 1024 * 2;
    float* x1  = (float*)p; p += (size_t)4096 * 1024 * 4;
    bf16* y1   = (bf16*)p; p += (size_t)4096 * 1024 * 2;
    bf16* h    = (bf16*)p; p += (size_t)4096 * 4096 * 2;

    const dim3 tb(32, 8);
    // weights -> bf16, transposed to [N][K]
    transpose_cast<<<dim3(32, 32), tb, 0, stream>>>(wq, Wqkv, 1024, 1024);
    transpose_cast<<<dim3(32, 32), tb, 0, stream>>>(wk, Wqkv + (size_t)1024 * 1024, 1024, 1024);
    transpose_cast<<<dim3(32, 32), tb, 0, stream>>>(wv, Wqkv + (size_t)2048 * 1024, 1024, 1024);
    transpose_cast<<<dim3(32, 32), tb, 0, stream>>>(wo, Wot, 1024, 1024);
    transpose_cast<<<dim3(128, 32), tb, 0, stream>>>(w0, W0t, 1024, 4096);
    transpose_cast<<<dim3(32, 128), tb, 0, stream>>>(w1, W1t, 4096, 1024);

    ln_kernel<<<4096, 256, 0, stream>>>(x, ln0s, ln0b, y0);

    // fused QKV projection: [4096,1024] @ [1024,3072]
    gemm_kernel<0, 128, 128, 4><<<dim3(24, 32), 256, 0, stream>>>(
        y0, Wqkv, 4096, 3072, 1024, bq, bk, bv, nullptr, qbuf, kbuf, vbuf, nullptr);

    transpose_v<<<dim3(2, 64, 32), tb, 0, stream>>>(vbuf, vtb);

    attn_kernel<<<dim3(32, 32), 256, 0, stream>>>(qbuf, kbuf, vtb, enc);

    // out projection + residual -> x1 (fp32): 128x64 tile, 512 wg = 2/CU
    gemm_kernel<1, 128, 64, 4><<<dim3(16, 32), 256, 0, stream>>>(
        enc, Wot, 4096, 1024, 1024, bo, nullptr, nullptr, x, nullptr, nullptr, nullptr, x1);

    ln_kernel<<<4096, 256, 0, stream>>>(x1, ln1s, ln1b, y1);

    // MLP up + GELU -> h (bf16): 128x128 tile, 1024 wg = 2 blocks/CU resident
    gemm_kernel<2, 128, 128, 4><<<dim3(32, 32), 256, 0, stream>>>(
        y1, W0t, 4096, 4096, 1024, b0, nullptr, nullptr, nullptr, h, nullptr, nullptr, nullptr);

    // MLP down + bias + residual -> out (fp32): 128x64 tile, 512 wg = 2/CU
    gemm_kernel<1, 128, 64, 4><<<dim3(16, 32), 256, 0, stream>>>(
        h, W1t, 4096, 1024, 4096, b1, nullptr, nullptr, x1, nullptr, nullptr, nullptr, out);
}

// Round 11
// 277.690 us; speedup vs baseline: 1.2495x; 1.0057x over previous
//
#include <hip/hip_runtime.h>
#include <cstdint>
#include <cstddef>

typedef __bf16 bf16;
typedef __attribute__((ext_vector_type(8))) __bf16 bf16x8;
typedef __attribute__((ext_vector_type(4))) __bf16 bf16x4;
typedef __attribute__((ext_vector_type(4))) float f32x4;

#define MFMA16 __builtin_amdgcn_mfma_f32_16x16x32_bf16

// async global -> LDS, 16B per lane. LDS dest is base + lane*16.
__device__ __forceinline__ void gload16(const bf16* g, bf16* l) {
    __builtin_amdgcn_global_load_lds(
        (const __attribute__((address_space(1))) uint32_t*)g,
        (__attribute__((address_space(3))) uint32_t*)l, 16, 0, 0);
}

// pack two f32 -> u32 of 2 bf16 (elem0 = lo bits)
__device__ __forceinline__ unsigned pk2(float lo, float hi) {
    union { bf16 h[2]; unsigned u; } c;
    c.h[0] = (bf16)lo; c.h[1] = (bf16)hi;
    return c.u;
}
// raw v_exp_f32: 2^x
__device__ __forceinline__ float fexp2(float x) {
    float r;
    asm("v_exp_f32 %0, %1" : "=v"(r) : "v"(x));
    return r;
}
// v_max3_f32 (T17)
__device__ __forceinline__ float fmax3(float a, float b, float c) {
    float r;
    asm("v_max3_f32 %0, %1, %2, %3" : "=v"(r) : "v"(a), "v"(b), "v"(c));
    return r;
}

// bijective XCD chunk swizzle (nwg % 8 == 0)
__device__ __forceinline__ int xcd_swz(int id, int nwg) {
    return (id & 7) * (nwg >> 3) + (id >> 3);
}

#define SBAR()  __builtin_amdgcn_s_barrier()
#define SCHED() __builtin_amdgcn_sched_barrier(0)

// ---------------------------------------------------------------------------
// Tiled transpose + fp32->bf16 cast:  src [K][N] fp32  ->  dst [N][K] bf16
// ---------------------------------------------------------------------------
__global__ __launch_bounds__(256) void transpose_cast(
    const float* __restrict__ src, bf16* __restrict__ dst, int K, int N)
{
    __shared__ float t[32][33];
    const int n0 = blockIdx.x * 32, k0 = blockIdx.y * 32;
    const int tx = threadIdx.x, ty = threadIdx.y;
    #pragma unroll
    for (int i = ty; i < 32; i += 8)
        t[i][tx] = src[(size_t)(k0 + i) * N + n0 + tx];
    __syncthreads();
    #pragma unroll
    for (int i = ty; i < 32; i += 8)
        dst[(size_t)(n0 + i) * K + k0 + tx] = (bf16)t[tx][i];
}

// ---------------------------------------------------------------------------
// Batched bf16 transpose for V: src [Z][2048][64] -> dst [Z][64][2048]
// ---------------------------------------------------------------------------
__global__ __launch_bounds__(256) void transpose_v(
    const bf16* __restrict__ src, bf16* __restrict__ dst)
{
    __shared__ bf16 t[32][33];
    const int z = blockIdx.z;
    const int h0 = blockIdx.x * 32, s0 = blockIdx.y * 32;
    const bf16* sp = src + (size_t)z * 2048 * 64;
    bf16* dp = dst + (size_t)z * 64 * 2048;
    const int tx = threadIdx.x, ty = threadIdx.y;
    #pragma unroll
    for (int i = ty; i < 32; i += 8)
        t[i][tx] = sp[(size_t)(s0 + i) * 64 + h0 + tx];
    __syncthreads();
    #pragma unroll
    for (int i = ty; i < 32; i += 8)
        dp[(size_t)(h0 + i) * 2048 + s0 + tx] = t[tx][i];
}

// ---------------------------------------------------------------------------
// LayerNorm (D=1024) fp32 in -> bf16 out. One block (256 thr) per row.
// ---------------------------------------------------------------------------
__global__ __launch_bounds__(256) void ln_kernel(
    const float* __restrict__ x, const float* __restrict__ sc,
    const float* __restrict__ bi, bf16* __restrict__ y)
{
    const int row = blockIdx.x, tid = threadIdx.x;
    const f32x4 v = ((const f32x4*)(x + (size_t)row * 1024))[tid];
    float s  = v[0] + v[1] + v[2] + v[3];
    float s2 = v[0]*v[0] + v[1]*v[1] + v[2]*v[2] + v[3]*v[3];
    #pragma unroll
    for (int d = 1; d < 64; d <<= 1) {
        s  += __shfl_xor(s, d);
        s2 += __shfl_xor(s2, d);
    }
    __shared__ float red[8];
    if ((tid & 63) == 0) { red[tid >> 6] = s; red[4 + (tid >> 6)] = s2; }
    __syncthreads();
    s  = red[0] + red[1] + red[2] + red[3];
    s2 = red[4] + red[5] + red[6] + red[7];
    const float mu = s * (1.f / 1024.f);
    const float rstd = rsqrtf(s2 * (1.f / 1024.f) - mu * mu + 1e-6f);
    const f32x4 s4 = ((const f32x4*)sc)[tid];
    const f32x4 b4 = ((const f32x4*)bi)[tid];
    bf16x4 o;
    #pragma unroll
    for (int j = 0; j < 4; ++j)
        o[j] = (bf16)((v[j] - mu) * rstd * s4[j] + b4[j]);
    ((bf16x4*)(y + (size_t)row * 1024))[tid] = o;
}

// ---------------------------------------------------------------------------
// bf16 GEMM, dbuf + COUNTED vmcnt + st_16x32-style swizzle (R8-R10-validated,
// unchanged). Tile BM x BN, BK=64, NW waves.
// ---------------------------------------------------------------------------
template <int EPI, int BM, int BN, int NW>
__global__ __launch_bounds__(NW * 64, 2) void gemm_kernel(
    const bf16* __restrict__ A, const bf16* __restrict__ Bt,
    int M, int N, int K,
    const float* __restrict__ b0, const float* __restrict__ b1,
    const float* __restrict__ b2, const float* __restrict__ res,
    bf16* __restrict__ o0, bf16* __restrict__ o1, bf16* __restrict__ o2,
    float* __restrict__ of)
{
    constexpr int NRW    = NW / 2;          // wave cols
    constexpr int MR     = BM / 32;         // row frags/wave
    constexpr int NR     = BN / 16 / NRW;   // col frags/wave
    constexpr int ACALLS = BM / (8 * NW);   // stage calls for A
    constexpr int BCALLS = BN / (8 * NW);   // stage calls for B
    constexpr int NLOADS = ACALLS + BCALLS; // gload16 per stage per wave
    static_assert(NLOADS == 8 || NLOADS == 6, "vmcnt literal");
    __shared__ bf16 As[2][BM * 64];
    __shared__ bf16 Bs[2][BN * 64];

    const int tid = threadIdx.x;
    const int wave = tid >> 6, lane = tid & 63;
    const int wr = (wave / NRW) * (MR * 16), wc = (wave % NRW) * (NR * 16);
    const int lr = lane & 15, lg = lane >> 4;

    const int nwg = gridDim.x * gridDim.y;
    const int id = xcd_swz(blockIdx.y * gridDim.x + blockIdx.x, nwg);
    const int bm = (id / gridDim.x) * BM, bn = (id % gridDim.x) * BN;

    f32x4 acc[MR][NR] = {};

    const int srow = tid >> 3;
    const int scol = ((tid & 7) * 8) ^ (((tid >> 5) & 1) << 4);
    const bf16* Ag = A  + (size_t)(bm + srow) * K + scol;
    const bf16* Bg = Bt + (size_t)(bn + srow) * K + scol;

    auto stage = [&](int buf, int k0) {
        #pragma unroll
        for (int c = 0; c < ACALLS; ++c)
            gload16(Ag + (size_t)(c * 8 * NW) * K + k0,
                    &As[buf][(c * 8 * NW) * 64] + (size_t)tid * 8);
        #pragma unroll
        for (int c = 0; c < BCALLS; ++c)
            gload16(Bg + (size_t)(c * 8 * NW) * K + k0,
                    &Bs[buf][(c * 8 * NW) * 64] + (size_t)tid * 8);
    };

    const int rsw = ((lane >> 2) & 1) << 4;
    const int ko0 = (lg * 8) ^ rsw;          // kh = 0
    const int ko1 = (32 + lg * 8) ^ rsw;     // kh = 1

    const int nk = K >> 6;
    stage(0, 0);
    __syncthreads();                          // prologue: full drain once
    int cur = 0;
    for (int i = 0; i < nk; ++i) {
        if (i + 1 < nk) {
            stage(cur ^ 1, (i + 1) << 6);     // loads fly under this iter
            SCHED();
            if constexpr (NLOADS == 8)
                asm volatile("s_waitcnt vmcnt(8)" ::: "memory");
            else
                asm volatile("s_waitcnt vmcnt(6)" ::: "memory");
        } else {
            asm volatile("s_waitcnt vmcnt(0)" ::: "memory");
        }
        SCHED();
        SBAR();                               // all waves gated -> tile i live
        SCHED();
        #pragma unroll
        for (int kh = 0; kh < 2; ++kh) {
            const int ko = kh ? ko1 : ko0;
            bf16x8 a[MR], b[NR];
            #pragma unroll
            for (int m = 0; m < MR; ++m)
                a[m] = *(const bf16x8*)&As[cur][(wr + m * 16 + lr) * 64 + ko];
            #pragma unroll
            for (int n = 0; n < NR; ++n)
                b[n] = *(const bf16x8*)&Bs[cur][(wc + n * 16 + lr) * 64 + ko];
            #pragma unroll
            for (int m = 0; m < MR; ++m)
                #pragma unroll
                for (int n = 0; n < NR; ++n)
                    acc[m][n] = MFMA16(a[m], b[n], acc[m][n], 0, 0, 0);
        }
        SCHED();
        asm volatile("s_waitcnt lgkmcnt(0)" ::: "memory");    // reads done
        SCHED();
        SBAR();                               // buf[cur] free for overwrite
        SCHED();
        cur ^= 1;
    }

    const int rbase = bm + wr + (lg << 2);
    const int cbase = bn + wc + lr;
    #pragma unroll
    for (int m = 0; m < MR; ++m) {
        #pragma unroll
        for (int n = 0; n < NR; ++n) {
            const f32x4 v = acc[m][n];
            #pragma unroll
            for (int r = 0; r < 4; ++r) {
                const int row = rbase + m * 16 + r;
                const int col = cbase + n * 16;
                const float val = v[r];
                if constexpr (EPI == 0) {
                    const int which = col >> 10, cc = col & 1023;
                    const float* bp = (which == 0) ? b0 : (which == 1) ? b1 : b2;
                    bf16* dp = (which == 0) ? o0 : (which == 1) ? o1 : o2;
                    // Q pre-scaled by H^-0.5 * log2(e) for exp2-domain softmax
                    const float scl = (which == 0) ? 0.18033688011112042f : 1.0f;
                    const int bb = row >> 11, t = row & 2047;
                    const int nh = cc >> 6, hh = cc & 63;
                    dp[(((size_t)(bb * 16 + nh) * 2048 + t) << 6) + hh] =
                        (bf16)((val + bp[cc]) * scl);
                } else if constexpr (EPI == 1) {
                    of[(size_t)row * N + col] =
                        val + b0[col] + res[(size_t)row * N + col];
                } else {
                    const float xg = val + b0[col];
                    const float z2 = 1.5957691216f * (xg + 0.044715f * xg * xg * xg);
                    o0[(size_t)row * N + col] = (bf16)(xg / (1.f + __expf(-z2)));
                }
            }
        }
    }
}

// ---------------------------------------------------------------------------
// Flash attention, KVBLK=128: swapped-QK^T + in-register softmax +
// sigma-permuted V (R10-validated per 64-half) + l-via-ones-MFMA.
// Per iter: {issue K(t+1) loads} QK^T -> softmax/frags -> barrier A ->
// {write Ks, issue V(t+1) loads} -> PV + L-MFMA -> barrier B -> {write Vs}.
// Q read directly global->regs (no Q LDS). 16 iters, 2 barriers each.
// ---------------------------------------------------------------------------
__global__ __launch_bounds__(256) void attn_kernel(
    const bf16* __restrict__ q, const bf16* __restrict__ k,
    const bf16* __restrict__ vt, bf16* __restrict__ enc)
{
    __shared__ bf16 Ks[2][64][72];
    __shared__ bf16 Vs[2][64][72];    // [half][h][sigma-permuted s-slot]

    const int tid = threadIdx.x, wave = tid >> 6, lane = tid & 63;
    const int lr = lane & 15, lk = (lane >> 4) * 8;
    const int qsel = (lane >> 4) << 2;
    const int id = xcd_swz(blockIdx.y * gridDim.x + blockIdx.x, 1024);
    const int qt = id % 32, z = id / 32;
    const bf16* qb = q + ((size_t)z * 2048 + qt * 64) * 64;
    const bf16* kb = k + (size_t)z * 2048 * 64;
    const bf16* vb = vt + (size_t)z * 64 * 2048;

    const int sr = tid >> 3, so = (tid & 7) * 8;
    // V permuted write base within a 64-col half (R10-validated)
    const int vb0 = (so & 32) + ((so >> 4) & 1) * 4 + ((so >> 3) & 1) * 16;

    union V8 { bf16x8 v; bf16x4 h[2]; };
    bf16x8 kr[4];
    V8 vr[4];

    auto load_k = [&](int st) {
        #pragma unroll
        for (int c = 0; c < 4; ++c)
            kr[c] = *(const bf16x8*)&kb[(size_t)(st * 128 + c * 32 + sr) * 64 + so];
    };
    auto write_k = [&]() {
        #pragma unroll
        for (int c = 0; c < 4; ++c)
            *(bf16x8*)&Ks[c >> 1][(c & 1) * 32 + sr][so] = kr[c];
    };
    auto load_v = [&](int st) {
        #pragma unroll
        for (int c = 0; c < 4; ++c)
            vr[c].v = *(const bf16x8*)
                &vb[(size_t)((c & 1) * 32 + sr) * 2048 + st * 128 + (c >> 1) * 64 + so];
    };
    auto write_v = [&]() {
        #pragma unroll
        for (int c = 0; c < 4; ++c) {
            *(bf16x4*)&Vs[c >> 1][(c & 1) * 32 + sr][vb0]     = vr[c].h[0];
            *(bf16x4*)&Vs[c >> 1][(c & 1) * 32 + sr][vb0 + 8] = vr[c].h[1];
        }
    };

    load_k(0); load_v(0);
    write_k(); write_v();
    __syncthreads();

    const bf16x8 aq0 = *(const bf16x8*)&qb[(wave * 16 + lr) * 64 + lk];
    const bf16x8 aq1 = *(const bf16x8*)&qb[(wave * 16 + lr) * 64 + 32 + lk];

    bf16x8 ones;
    #pragma unroll
    for (int i = 0; i < 8; ++i) ones[i] = (bf16)1.0f;

    float m_run = -1e30f;
    f32x4 accO[4] = {};
    f32x4 accL = {};

    for (int kt = 0; kt < 16; ++kt) {
        if (kt < 15) load_k(kt + 1);     // flies under QK^T + softmax

        f32x4 p[8];
        __builtin_amdgcn_s_setprio(1);
        #pragma unroll
        for (int h = 0; h < 2; ++h)
            #pragma unroll
            for (int j = 0; j < 4; ++j) {
                f32x4 t = {};
                t = MFMA16(*(const bf16x8*)&Ks[h][j * 16 + lr][lk],      aq0, t, 0, 0, 0);
                t = MFMA16(*(const bf16x8*)&Ks[h][j * 16 + lr][32 + lk], aq1, t, 0, 0, 0);
                p[h * 4 + j] = t;
            }
        __builtin_amdgcn_s_setprio(0);

        // row max over 32 values (v_max3 chain) + 2 cross-group shuffles
        float pmax = fmax3(p[0][0], p[0][1], p[0][2]);
        pmax = fmax3(pmax, p[0][3], p[1][0]);
        pmax = fmax3(pmax, p[1][1], p[1][2]);
        pmax = fmax3(pmax, p[1][3], p[2][0]);
        pmax = fmax3(pmax, p[2][1], p[2][2]);
        pmax = fmax3(pmax, p[2][3], p[3][0]);
        pmax = fmax3(pmax, p[3][1], p[3][2]);
        pmax = fmax3(pmax, p[3][3], p[4][0]);
        pmax = fmax3(pmax, p[4][1], p[4][2]);
        pmax = fmax3(pmax, p[4][3], p[5][0]);
        pmax = fmax3(pmax, p[5][1], p[5][2]);
        pmax = fmax3(pmax, p[5][3], p[6][0]);
        pmax = fmax3(pmax, p[6][1], p[6][2]);
        pmax = fmax3(pmax, p[6][3], p[7][0]);
        pmax = fmax3(pmax, p[7][1], p[7][2]);
        pmax = fmaxf(pmax, p[7][3]);
        pmax = fmaxf(pmax, __shfl_xor(pmax, 16));
        pmax = fmaxf(pmax, __shfl_xor(pmax, 32));

        // defer-max (log2 domain, THR = 8*log2e)
        if (__any(pmax - m_run > 11.54f)) {
            const float mnew = fmaxf(m_run, pmax);
            const float fac = fexp2(m_run - mnew);
            m_run = mnew;
            float facq[4];
            #pragma unroll
            for (int r = 0; r < 4; ++r) facq[r] = __shfl(fac, qsel + r);
            #pragma unroll
            for (int nh = 0; nh < 4; ++nh)
                #pragma unroll
                for (int r = 0; r < 4; ++r) accO[nh][r] *= facq[r];
            #pragma unroll
            for (int r = 0; r < 4; ++r) accL[r] *= facq[r];
        }

        #pragma unroll
        for (int jj = 0; jj < 8; ++jj)
            #pragma unroll
            for (int r = 0; r < 4; ++r)
                p[jj][r] = fexp2(p[jj][r] - m_run);

        // sigma-permuted A-frags from the lane's own registers (no x-lane ops)
        union FW { unsigned u[4]; bf16x8 v; } fq[4];
        #pragma unroll
        for (int q2 = 0; q2 < 4; ++q2) {
            fq[q2].u[0] = pk2(p[2 * q2][0],     p[2 * q2][1]);
            fq[q2].u[1] = pk2(p[2 * q2][2],     p[2 * q2][3]);
            fq[q2].u[2] = pk2(p[2 * q2 + 1][0], p[2 * q2 + 1][1]);
            fq[q2].u[3] = pk2(p[2 * q2 + 1][2], p[2 * q2 + 1][3]);
        }

        __syncthreads();                 // barrier A: Ks reads done
        if (kt < 15) { write_k(); load_v(kt + 1); }

        __builtin_amdgcn_s_setprio(1);
        #pragma unroll
        for (int q2 = 0; q2 < 4; ++q2) {
            #pragma unroll
            for (int nh = 0; nh < 4; ++nh)
                accO[nh] = MFMA16(fq[q2].v,
                    *(const bf16x8*)&Vs[q2 >> 1][nh * 16 + lr][(q2 & 1) * 32 + lk],
                    accO[nh], 0, 0, 0);
            accL = MFMA16(fq[q2].v, ones, accL, 0, 0, 0);   // l row-sums
        }
        __builtin_amdgcn_s_setprio(0);

        __syncthreads();                 // barrier B: Vs reads + K writes done
        if (kt < 15) write_v();
    }

    const int bb = z >> 4, nn = z & 15;
    #pragma unroll
    for (int nh = 0; nh < 4; ++nh)
        #pragma unroll
        for (int r = 0; r < 4; ++r) {
            const int t = qt * 64 + wave * 16 + qsel + r;
            const int hh = nh * 16 + lr;
            enc[((size_t)(bb * 2048 + t)) * 1024 + nn * 64 + hh] =
                (bf16)(accO[nh][r] / accL[r]);
        }
}

// ---------------------------------------------------------------------------
extern "C" void kernel_launch(void* const* d_in, const int* in_sizes, int n_in,
                              void* d_out, int out_size, void* d_ws, size_t ws_size,
                              hipStream_t stream) {
    const float* x    = (const float*)d_in[0];
    const float* ln0s = (const float*)d_in[1];
    const float* ln0b = (const float*)d_in[2];
    const float* ln1s = (const float*)d_in[3];
    const float* ln1b = (const float*)d_in[4];
    const float* wq   = (const float*)d_in[5];
    const float* bq   = (const float*)d_in[6];
    const float* wk   = (const float*)d_in[7];
    const float* bk   = (const float*)d_in[8];
    const float* wv   = (const float*)d_in[9];
    const float* bv   = (const float*)d_in[10];
    const float* wo   = (const float*)d_in[11];
    const float* bo   = (const float*)d_in[12];
    const float* w0   = (const float*)d_in[13];
    const float* b0   = (const float*)d_in[14];
    const float* w1   = (const float*)d_in[15];
    const float* b1   = (const float*)d_in[16];
    float* out = (float*)d_out;

    // workspace layout (128 MiB)
    char* p = (char*)d_ws;
    bf16* Wqkv = (bf16*)p; p += (size_t)3072 * 1024 * 2;
    bf16* Wot  = (bf16*)p; p += (size_t)1024 * 1024 * 2;
    bf16* W0t  = (bf16*)p; p += (size_t)4096 * 1024 * 2;
    bf16* W1t  = (bf16*)p; p += (size_t)1024 * 4096 * 2;
    bf16* y0   = (bf16*)p; p += (size_t)4096 * 1024 * 2;
    bf16* qbuf = (bf16*)p; p += (size_t)4096 * 1024 * 2;
    bf16* kbuf = (bf16*)p; p += (size_t)4096 * 1024 * 2;
    bf16* vbuf = (bf16*)p; p += (size_t)4096 * 1024 * 2;
    bf16* vtb  = (bf16*)p; p += (size_t)4096 * 1024 * 2;
    bf16* enc  = (bf16*)p; p += (size_t)4096 * 1024 * 2;
    float* x1  = (float*)p; p += (size_t)4096 * 1024 * 4;
    bf16* y1   = (bf16*)p; p += (size_t)4096 * 1024 * 2;
    bf16* h    = (bf16*)p; p += (size_t)4096 * 4096 * 2;

    const dim3 tb(32, 8);
    // weights -> bf16, transposed to [N][K]
    transpose_cast<<<dim3(32, 32), tb, 0, stream>>>(wq, Wqkv, 1024, 1024);
    transpose_cast<<<dim3(32, 32), tb, 0, stream>>>(wk, Wqkv + (size_t)1024 * 1024, 1024, 1024);
    transpose_cast<<<dim3(32, 32), tb, 0, stream>>>(wv, Wqkv + (size_t)2048 * 1024, 1024, 1024);
    transpose_cast<<<dim3(32, 32), tb, 0, stream>>>(wo, Wot, 1024, 1024);
    transpose_cast<<<dim3(128, 32), tb, 0, stream>>>(w0, W0t, 1024, 4096);
    transpose_cast<<<dim3(32, 128), tb, 0, stream>>>(w1, W1t, 4096, 1024);

    ln_kernel<<<4096, 256, 0, stream>>>(x, ln0s, ln0b, y0);

    // fused QKV projection: [4096,1024] @ [1024,3072]
    gemm_kernel<0, 128, 128, 4><<<dim3(24, 32), 256, 0, stream>>>(
        y0, Wqkv, 4096, 3072, 1024, bq, bk, bv, nullptr, qbuf, kbuf, vbuf, nullptr);

    transpose_v<<<dim3(2, 64, 32), tb, 0, stream>>>(vbuf, vtb);

    attn_kernel<<<dim3(32, 32), 256, 0, stream>>>(qbuf, kbuf, vtb, enc);

    // out projection + residual -> x1 (fp32): 128x64 tile, 512 wg = 2/CU
    gemm_kernel<1, 128, 64, 4><<<dim3(16, 32), 256, 0, stream>>>(
        enc, Wot, 4096, 1024, 1024, bo, nullptr, nullptr, x, nullptr, nullptr, nullptr, x1);

    ln_kernel<<<4096, 256, 0, stream>>>(x1, ln1s, ln1b, y1);

    // MLP up + GELU -> h (bf16): 128x128 tile, 1024 wg = 2 blocks/CU resident
    gemm_kernel<2, 128, 128, 4><<<dim3(32, 32), 256, 0, stream>>>(
        y1, W0t, 4096, 4096, 1024, b0, nullptr, nullptr, nullptr, h, nullptr, nullptr, nullptr);

    // MLP down + bias + residual -> out (fp32): 128x64 tile, 512 wg = 2/CU
    gemm_kernel<1, 128, 64, 4><<<dim3(16, 32), 256, 0, stream>>>(
        h, W1t, 4096, 1024, 4096, b1, nullptr, nullptr, x1, nullptr, nullptr, nullptr, out);
}

// Round 12
// 262.688 us; speedup vs baseline: 1.3208x; 1.0571x over previous
//
#include <hip/hip_runtime.h>
#include <cstdint>
#include <cstddef>

typedef __bf16 bf16;
typedef __attribute__((ext_vector_type(8))) __bf16 bf16x8;
typedef __attribute__((ext_vector_type(4))) __bf16 bf16x4;
typedef __attribute__((ext_vector_type(4))) float f32x4;

#define MFMA16 __builtin_amdgcn_mfma_f32_16x16x32_bf16

// async global -> LDS, 16B per lane. LDS dest is base + lane*16.
__device__ __forceinline__ void gload16(const bf16* g, bf16* l) {
    __builtin_amdgcn_global_load_lds(
        (const __attribute__((address_space(1))) uint32_t*)g,
        (__attribute__((address_space(3))) uint32_t*)l, 16, 0, 0);
}

// pack two f32 -> u32 of 2 bf16 (elem0 = lo bits)
__device__ __forceinline__ unsigned pk2(float lo, float hi) {
    union { bf16 h[2]; unsigned u; } c;
    c.h[0] = (bf16)lo; c.h[1] = (bf16)hi;
    return c.u;
}
// raw v_exp_f32: 2^x
__device__ __forceinline__ float fexp2(float x) {
    float r;
    asm("v_exp_f32 %0, %1" : "=v"(r) : "v"(x));
    return r;
}
// v_max3_f32 (T17)
__device__ __forceinline__ float fmax3(float a, float b, float c) {
    float r;
    asm("v_max3_f32 %0, %1, %2, %3" : "=v"(r) : "v"(a), "v"(b), "v"(c));
    return r;
}

// bijective XCD chunk swizzle (nwg % 8 == 0)
__device__ __forceinline__ int xcd_swz(int id, int nwg) {
    return (id & 7) * (nwg >> 3) + (id >> 3);
}

#define SBAR()  __builtin_amdgcn_s_barrier()
#define SCHED() __builtin_amdgcn_sched_barrier(0)

// ---------------------------------------------------------------------------
// Fused weight prep: all 6 transposes+casts in ONE launch.
// Tile t of weight w: src [K][N] fp32 -> dst [N][K] bf16, 32x32 tiles.
// ---------------------------------------------------------------------------
__global__ __launch_bounds__(256) void transpose_all(
    const float* __restrict__ wq, const float* __restrict__ wk,
    const float* __restrict__ wv, const float* __restrict__ wo,
    const float* __restrict__ w0, const float* __restrict__ w1,
    bf16* __restrict__ Wqkv, bf16* __restrict__ Wot,
    bf16* __restrict__ W0t, bf16* __restrict__ W1t)
{
    __shared__ float t[32][33];
    const int b = blockIdx.x;
    const float* src;
    bf16* dst;
    int K, N, tt;
    if (b < 1024)      { src = wq; dst = Wqkv;                       K = 1024; N = 1024; tt = b; }
    else if (b < 2048) { src = wk; dst = Wqkv + (size_t)1024 * 1024; K = 1024; N = 1024; tt = b - 1024; }
    else if (b < 3072) { src = wv; dst = Wqkv + (size_t)2048 * 1024; K = 1024; N = 1024; tt = b - 2048; }
    else if (b < 4096) { src = wo; dst = Wot;                        K = 1024; N = 1024; tt = b - 3072; }
    else if (b < 8192) { src = w0; dst = W0t;                        K = 1024; N = 4096; tt = b - 4096; }
    else               { src = w1; dst = W1t;                        K = 4096; N = 1024; tt = b - 8192; }
    const int ntx = N >> 5;
    const int n0 = (tt % ntx) * 32, k0 = (tt / ntx) * 32;
    const int tx = threadIdx.x, ty = threadIdx.y;
    #pragma unroll
    for (int i = ty; i < 32; i += 8)
        t[i][tx] = src[(size_t)(k0 + i) * N + n0 + tx];
    __syncthreads();
    #pragma unroll
    for (int i = ty; i < 32; i += 8)
        dst[(size_t)(n0 + i) * K + k0 + tx] = (bf16)t[tx][i];
}

// ---------------------------------------------------------------------------
// Batched bf16 transpose for V: src [Z][2048][64] -> dst [Z][64][2048]
// ---------------------------------------------------------------------------
__global__ __launch_bounds__(256) void transpose_v(
    const bf16* __restrict__ src, bf16* __restrict__ dst)
{
    __shared__ bf16 t[32][33];
    const int z = blockIdx.z;
    const int h0 = blockIdx.x * 32, s0 = blockIdx.y * 32;
    const bf16* sp = src + (size_t)z * 2048 * 64;
    bf16* dp = dst + (size_t)z * 64 * 2048;
    const int tx = threadIdx.x, ty = threadIdx.y;
    #pragma unroll
    for (int i = ty; i < 32; i += 8)
        t[i][tx] = sp[(size_t)(s0 + i) * 64 + h0 + tx];
    __syncthreads();
    #pragma unroll
    for (int i = ty; i < 32; i += 8)
        dp[(size_t)(h0 + i) * 2048 + s0 + tx] = t[tx][i];
}

// ---------------------------------------------------------------------------
// LayerNorm (D=1024) fp32 in -> bf16 out. One block (256 thr) per row.
// ---------------------------------------------------------------------------
__global__ __launch_bounds__(256) void ln_kernel(
    const float* __restrict__ x, const float* __restrict__ sc,
    const float* __restrict__ bi, bf16* __restrict__ y)
{
    const int row = blockIdx.x, tid = threadIdx.x;
    const f32x4 v = ((const f32x4*)(x + (size_t)row * 1024))[tid];
    float s  = v[0] + v[1] + v[2] + v[3];
    float s2 = v[0]*v[0] + v[1]*v[1] + v[2]*v[2] + v[3]*v[3];
    #pragma unroll
    for (int d = 1; d < 64; d <<= 1) {
        s  += __shfl_xor(s, d);
        s2 += __shfl_xor(s2, d);
    }
    __shared__ float red[8];
    if ((tid & 63) == 0) { red[tid >> 6] = s; red[4 + (tid >> 6)] = s2; }
    __syncthreads();
    s  = red[0] + red[1] + red[2] + red[3];
    s2 = red[4] + red[5] + red[6] + red[7];
    const float mu = s * (1.f / 1024.f);
    const float rstd = rsqrtf(s2 * (1.f / 1024.f) - mu * mu + 1e-6f);
    const f32x4 s4 = ((const f32x4*)sc)[tid];
    const f32x4 b4 = ((const f32x4*)bi)[tid];
    bf16x4 o;
    #pragma unroll
    for (int j = 0; j < 4; ++j)
        o[j] = (bf16)((v[j] - mu) * rstd * s4[j] + b4[j]);
    ((bf16x4*)(y + (size_t)row * 1024))[tid] = o;
}

// ---------------------------------------------------------------------------
// bf16 GEMM, dbuf + COUNTED vmcnt + st_16x32-style swizzle (R8-R11-validated,
// unchanged). Tile BM x BN, BK=64, NW waves.
// ---------------------------------------------------------------------------
template <int EPI, int BM, int BN, int NW>
__global__ __launch_bounds__(NW * 64, 2) void gemm_kernel(
    const bf16* __restrict__ A, const bf16* __restrict__ Bt,
    int M, int N, int K,
    const float* __restrict__ b0, const float* __restrict__ b1,
    const float* __restrict__ b2, const float* __restrict__ res,
    bf16* __restrict__ o0, bf16* __restrict__ o1, bf16* __restrict__ o2,
    float* __restrict__ of)
{
    constexpr int NRW    = NW / 2;          // wave cols
    constexpr int MR     = BM / 32;         // row frags/wave
    constexpr int NR     = BN / 16 / NRW;   // col frags/wave
    constexpr int ACALLS = BM / (8 * NW);   // stage calls for A
    constexpr int BCALLS = BN / (8 * NW);   // stage calls for B
    constexpr int NLOADS = ACALLS + BCALLS; // gload16 per stage per wave
    static_assert(NLOADS == 8 || NLOADS == 6, "vmcnt literal");
    __shared__ bf16 As[2][BM * 64];
    __shared__ bf16 Bs[2][BN * 64];

    const int tid = threadIdx.x;
    const int wave = tid >> 6, lane = tid & 63;
    const int wr = (wave / NRW) * (MR * 16), wc = (wave % NRW) * (NR * 16);
    const int lr = lane & 15, lg = lane >> 4;

    const int nwg = gridDim.x * gridDim.y;
    const int id = xcd_swz(blockIdx.y * gridDim.x + blockIdx.x, nwg);
    const int bm = (id / gridDim.x) * BM, bn = (id % gridDim.x) * BN;

    f32x4 acc[MR][NR] = {};

    const int srow = tid >> 3;
    const int scol = ((tid & 7) * 8) ^ (((tid >> 5) & 1) << 4);
    const bf16* Ag = A  + (size_t)(bm + srow) * K + scol;
    const bf16* Bg = Bt + (size_t)(bn + srow) * K + scol;

    auto stage = [&](int buf, int k0) {
        #pragma unroll
        for (int c = 0; c < ACALLS; ++c)
            gload16(Ag + (size_t)(c * 8 * NW) * K + k0,
                    &As[buf][(c * 8 * NW) * 64] + (size_t)tid * 8);
        #pragma unroll
        for (int c = 0; c < BCALLS; ++c)
            gload16(Bg + (size_t)(c * 8 * NW) * K + k0,
                    &Bs[buf][(c * 8 * NW) * 64] + (size_t)tid * 8);
    };

    const int rsw = ((lane >> 2) & 1) << 4;
    const int ko0 = (lg * 8) ^ rsw;          // kh = 0
    const int ko1 = (32 + lg * 8) ^ rsw;     // kh = 1

    const int nk = K >> 6;
    stage(0, 0);
    __syncthreads();                          // prologue: full drain once
    int cur = 0;
    for (int i = 0; i < nk; ++i) {
        if (i + 1 < nk) {
            stage(cur ^ 1, (i + 1) << 6);     // loads fly under this iter
            SCHED();
            if constexpr (NLOADS == 8)
                asm volatile("s_waitcnt vmcnt(8)" ::: "memory");
            else
                asm volatile("s_waitcnt vmcnt(6)" ::: "memory");
        } else {
            asm volatile("s_waitcnt vmcnt(0)" ::: "memory");
        }
        SCHED();
        SBAR();                               // all waves gated -> tile i live
        SCHED();
        #pragma unroll
        for (int kh = 0; kh < 2; ++kh) {
            const int ko = kh ? ko1 : ko0;
            bf16x8 a[MR], b[NR];
            #pragma unroll
            for (int m = 0; m < MR; ++m)
                a[m] = *(const bf16x8*)&As[cur][(wr + m * 16 + lr) * 64 + ko];
            #pragma unroll
            for (int n = 0; n < NR; ++n)
                b[n] = *(const bf16x8*)&Bs[cur][(wc + n * 16 + lr) * 64 + ko];
            #pragma unroll
            for (int m = 0; m < MR; ++m)
                #pragma unroll
                for (int n = 0; n < NR; ++n)
                    acc[m][n] = MFMA16(a[m], b[n], acc[m][n], 0, 0, 0);
        }
        SCHED();
        asm volatile("s_waitcnt lgkmcnt(0)" ::: "memory");    // reads done
        SCHED();
        SBAR();                               // buf[cur] free for overwrite
        SCHED();
        cur ^= 1;
    }

    const int rbase = bm + wr + (lg << 2);
    const int cbase = bn + wc + lr;
    #pragma unroll
    for (int m = 0; m < MR; ++m) {
        #pragma unroll
        for (int n = 0; n < NR; ++n) {
            const f32x4 v = acc[m][n];
            #pragma unroll
            for (int r = 0; r < 4; ++r) {
                const int row = rbase + m * 16 + r;
                const int col = cbase + n * 16;
                const float val = v[r];
                if constexpr (EPI == 0) {
                    const int which = col >> 10, cc = col & 1023;
                    const float* bp = (which == 0) ? b0 : (which == 1) ? b1 : b2;
                    bf16* dp = (which == 0) ? o0 : (which == 1) ? o1 : o2;
                    // Q pre-scaled by H^-0.5 * log2(e) for exp2-domain softmax
                    const float scl = (which == 0) ? 0.18033688011112042f : 1.0f;
                    const int bb = row >> 11, t = row & 2047;
                    const int nh = cc >> 6, hh = cc & 63;
                    dp[(((size_t)(bb * 16 + nh) * 2048 + t) << 6) + hh] =
                        (bf16)((val + bp[cc]) * scl);
                } else if constexpr (EPI == 1) {
                    of[(size_t)row * N + col] =
                        val + b0[col] + res[(size_t)row * N + col];
                } else {
                    const float xg = val + b0[col];
                    const float z2 = 1.5957691216f * (xg + 0.044715f * xg * xg * xg);
                    o0[(size_t)row * N + col] = (bf16)(xg / (1.f + __expf(-z2)));
                }
            }
        }
    }
}

// ---------------------------------------------------------------------------
// Flash attention (R10-validated structure: KVBLK=64, single K/V buffer,
// 2 barriers/tile, swapped-QK^T + in-register softmax + sigma-permuted V)
// + l-via-ones-MFMA (row sums in accumulator layout) + Q direct global->reg.
// ---------------------------------------------------------------------------
__global__ __launch_bounds__(256) void attn_kernel(
    const bf16* __restrict__ q, const bf16* __restrict__ k,
    const bf16* __restrict__ vt, bf16* __restrict__ enc)
{
    __shared__ bf16 Ks[64][72];
    __shared__ bf16 Vs[64][72];       // [h][sigma-permuted s-slot]

    const int tid = threadIdx.x, wave = tid >> 6, lane = tid & 63;
    const int lr = lane & 15, lk = (lane >> 4) * 8;
    const int qsel = (lane >> 4) << 2;
    const int id = xcd_swz(blockIdx.y * gridDim.x + blockIdx.x, 1024);
    const int qt = id % 32, z = id / 32;
    const bf16* qb = q + ((size_t)z * 2048 + qt * 64) * 64;
    const bf16* kb = k + (size_t)z * 2048 * 64;
    const bf16* vb = vt + (size_t)z * 64 * 2048;

    const int sr = tid >> 3, so = (tid & 7) * 8;
    // V permuted write base: slots b0..b0+3 and b0+8..b0+11 (R10-validated)
    const int vb0 = (so & 32) + ((so >> 4) & 1) * 4 + ((so >> 3) & 1) * 16;

    union V8 { bf16x8 v; bf16x4 h[2]; };
    bf16x8 kr0, kr1;
    V8 vr0, vr1;
    auto load_tile = [&](int st) {
        kr0 = *(const bf16x8*)&kb[(size_t)(st * 64 + sr) * 64 + so];
        kr1 = *(const bf16x8*)&kb[(size_t)(st * 64 + sr + 32) * 64 + so];
        vr0.v = *(const bf16x8*)&vb[(size_t)sr * 2048 + st * 64 + so];
        vr1.v = *(const bf16x8*)&vb[(size_t)(sr + 32) * 2048 + st * 64 + so];
    };
    auto write_tile = [&]() {
        *(bf16x8*)&Ks[sr][so]      = kr0;
        *(bf16x8*)&Ks[sr + 32][so] = kr1;
        *(bf16x4*)&Vs[sr][vb0]          = vr0.h[0];
        *(bf16x4*)&Vs[sr][vb0 + 8]      = vr0.h[1];
        *(bf16x4*)&Vs[sr + 32][vb0]     = vr1.h[0];
        *(bf16x4*)&Vs[sr + 32][vb0 + 8] = vr1.h[1];
    };

    load_tile(0);
    write_tile();
    // Q straight from global to regs (no Q LDS round-trip)
    const bf16x8 aq0 = *(const bf16x8*)&qb[(wave * 16 + lr) * 64 + lk];
    const bf16x8 aq1 = *(const bf16x8*)&qb[(wave * 16 + lr) * 64 + 32 + lk];
    __syncthreads();

    bf16x8 ones;
    #pragma unroll
    for (int i = 0; i < 8; ++i) ones[i] = (bf16)1.0f;

    float m_run = -1e30f;
    f32x4 accO[4] = {};
    f32x4 accL = {};

    for (int kt = 0; kt < 32; ++kt) {
        if (kt < 31) load_tile(kt + 1);   // reg prefetch under compute

        f32x4 p4[4] = {};
        __builtin_amdgcn_s_setprio(1);
        #pragma unroll
        for (int j = 0; j < 4; ++j) {
            p4[j] = MFMA16(*(const bf16x8*)&Ks[j * 16 + lr][lk],      aq0, p4[j], 0, 0, 0);
            p4[j] = MFMA16(*(const bf16x8*)&Ks[j * 16 + lr][32 + lk], aq1, p4[j], 0, 0, 0);
        }
        __builtin_amdgcn_s_setprio(0);

        // row max: v_max3 chain (T17) + 2 cross-group shuffles
        float pmax = fmax3(p4[0][0], p4[0][1], p4[0][2]);
        pmax = fmax3(pmax, p4[0][3], p4[1][0]);
        pmax = fmax3(pmax, p4[1][1], p4[1][2]);
        pmax = fmax3(pmax, p4[1][3], p4[2][0]);
        pmax = fmax3(pmax, p4[2][1], p4[2][2]);
        pmax = fmax3(pmax, p4[2][3], p4[3][0]);
        pmax = fmax3(pmax, p4[3][1], p4[3][2]);
        pmax = fmaxf(pmax, p4[3][3]);
        pmax = fmaxf(pmax, __shfl_xor(pmax, 16));
        pmax = fmaxf(pmax, __shfl_xor(pmax, 32));

        // defer-max (log2 domain, THR = 8*log2e)
        if (__any(pmax - m_run > 11.54f)) {
            const float mnew = fmaxf(m_run, pmax);
            const float fac = fexp2(m_run - mnew);
            m_run = mnew;
            float facq[4];
            #pragma unroll
            for (int r = 0; r < 4; ++r) facq[r] = __shfl(fac, qsel + r);
            #pragma unroll
            for (int nh = 0; nh < 4; ++nh)
                #pragma unroll
                for (int r = 0; r < 4; ++r) accO[nh][r] *= facq[r];
            #pragma unroll
            for (int r = 0; r < 4; ++r) accL[r] *= facq[r];
        }

        #pragma unroll
        for (int j = 0; j < 4; ++j)
            #pragma unroll
            for (int r = 0; r < 4; ++r)
                p4[j][r] = fexp2(p4[j][r] - m_run);

        // sigma-permuted A-frags from the lane's own registers (R10-validated)
        union FW { unsigned u[4]; bf16x8 v; } f0, f1;
        f0.u[0] = pk2(p4[0][0], p4[0][1]);
        f0.u[1] = pk2(p4[0][2], p4[0][3]);
        f0.u[2] = pk2(p4[1][0], p4[1][1]);
        f0.u[3] = pk2(p4[1][2], p4[1][3]);
        f1.u[0] = pk2(p4[2][0], p4[2][1]);
        f1.u[1] = pk2(p4[2][2], p4[2][3]);
        f1.u[2] = pk2(p4[3][0], p4[3][1]);
        f1.u[3] = pk2(p4[3][2], p4[3][3]);

        __builtin_amdgcn_s_setprio(1);
        #pragma unroll
        for (int nh = 0; nh < 4; ++nh) {
            accO[nh] = MFMA16(f0.v, *(const bf16x8*)&Vs[nh * 16 + lr][lk],      accO[nh], 0, 0, 0);
            accO[nh] = MFMA16(f1.v, *(const bf16x8*)&Vs[nh * 16 + lr][32 + lk], accO[nh], 0, 0, 0);
        }
        accL = MFMA16(f0.v, ones, accL, 0, 0, 0);   // l row-sums, acc layout
        accL = MFMA16(f1.v, ones, accL, 0, 0, 0);
        __builtin_amdgcn_s_setprio(0);

        __syncthreads();
        if (kt < 31) write_tile();
        __syncthreads();
    }

    const int bb = z >> 4, nn = z & 15;
    #pragma unroll
    for (int nh = 0; nh < 4; ++nh)
        #pragma unroll
        for (int r = 0; r < 4; ++r) {
            const int t = qt * 64 + wave * 16 + qsel + r;
            const int hh = nh * 16 + lr;
            enc[((size_t)(bb * 2048 + t)) * 1024 + nn * 64 + hh] =
                (bf16)(accO[nh][r] / accL[r]);
        }
}

// ---------------------------------------------------------------------------
extern "C" void kernel_launch(void* const* d_in, const int* in_sizes, int n_in,
                              void* d_out, int out_size, void* d_ws, size_t ws_size,
                              hipStream_t stream) {
    const float* x    = (const float*)d_in[0];
    const float* ln0s = (const float*)d_in[1];
    const float* ln0b = (const float*)d_in[2];
    const float* ln1s = (const float*)d_in[3];
    const float* ln1b = (const float*)d_in[4];
    const float* wq   = (const float*)d_in[5];
    const float* bq   = (const float*)d_in[6];
    const float* wk   = (const float*)d_in[7];
    const float* bk   = (const float*)d_in[8];
    const float* wv   = (const float*)d_in[9];
    const float* bv   = (const float*)d_in[10];
    const float* wo   = (const float*)d_in[11];
    const float* bo   = (const float*)d_in[12];
    const float* w0   = (const float*)d_in[13];
    const float* b0   = (const float*)d_in[14];
    const float* w1   = (const float*)d_in[15];
    const float* b1   = (const float*)d_in[16];
    float* out = (float*)d_out;

    // workspace layout (128 MiB)
    char* p = (char*)d_ws;
    bf16* Wqkv = (bf16*)p; p += (size_t)3072 * 1024 * 2;
    bf16* Wot  = (bf16*)p; p += (size_t)1024 * 1024 * 2;
    bf16* W0t  = (bf16*)p; p += (size_t)4096 * 1024 * 2;
    bf16* W1t  = (bf16*)p; p += (size_t)1024 * 4096 * 2;
    bf16* y0   = (bf16*)p; p += (size_t)4096 * 1024 * 2;
    bf16* qbuf = (bf16*)p; p += (size_t)4096 * 1024 * 2;
    bf16* kbuf = (bf16*)p; p += (size_t)4096 * 1024 * 2;
    bf16* vbuf = (bf16*)p; p += (size_t)4096 * 1024 * 2;
    bf16* vtb  = (bf16*)p; p += (size_t)4096 * 1024 * 2;
    bf16* enc  = (bf16*)p; p += (size_t)4096 * 1024 * 2;
    float* x1  = (float*)p; p += (size_t)4096 * 1024 * 4;
    bf16* y1   = (bf16*)p; p += (size_t)4096 * 1024 * 2;
    bf16* h    = (bf16*)p; p += (size_t)4096 * 4096 * 2;

    const dim3 tb(32, 8);
    // all weights -> bf16 [N][K] in ONE launch
    transpose_all<<<12288, tb, 0, stream>>>(wq, wk, wv, wo, w0, w1,
                                            Wqkv, Wot, W0t, W1t);

    ln_kernel<<<4096, 256, 0, stream>>>(x, ln0s, ln0b, y0);

    // fused QKV projection: [4096,1024] @ [1024,3072]
    gemm_kernel<0, 128, 128, 4><<<dim3(24, 32), 256, 0, stream>>>(
        y0, Wqkv, 4096, 3072, 1024, bq, bk, bv, nullptr, qbuf, kbuf, vbuf, nullptr);

    transpose_v<<<dim3(2, 64, 32), tb, 0, stream>>>(vbuf, vtb);

    attn_kernel<<<dim3(32, 32), 256, 0, stream>>>(qbuf, kbuf, vtb, enc);

    // out projection + residual -> x1 (fp32): 128x64 tile, 512 wg = 2/CU
    gemm_kernel<1, 128, 64, 4><<<dim3(16, 32), 256, 0, stream>>>(
        enc, Wot, 4096, 1024, 1024, bo, nullptr, nullptr, x, nullptr, nullptr, nullptr, x1);

    ln_kernel<<<4096, 256, 0, stream>>>(x1, ln1s, ln1b, y1);

    // MLP up + GELU -> h (bf16): 128x128 tile, 1024 wg = 2 blocks/CU resident
    gemm_kernel<2, 128, 128, 4><<<dim3(32, 32), 256, 0, stream>>>(
        y1, W0t, 4096, 4096, 1024, b0, nullptr, nullptr, nullptr, h, nullptr, nullptr, nullptr);

    // MLP down + bias + residual -> out (fp32): 128x64 tile, 512 wg = 2/CU
    gemm_kernel<1, 128, 64, 4><<<dim3(16, 32), 256, 0, stream>>>(
        h, W1t, 4096, 1024, 4096, b1, nullptr, nullptr, x1, nullptr, nullptr, nullptr, out);
}

// Round 13
// 253.585 us; speedup vs baseline: 1.3682x; 1.0359x over previous
//
#include <hip/hip_runtime.h>
#include <cstdint>
#include <cstddef>

typedef __bf16 bf16;
typedef __attribute__((ext_vector_type(8))) __bf16 bf16x8;
typedef __attribute__((ext_vector_type(4))) __bf16 bf16x4;
typedef __attribute__((ext_vector_type(4))) float f32x4;

#define MFMA16 __builtin_amdgcn_mfma_f32_16x16x32_bf16

// async global -> LDS, 16B per lane. LDS dest is base + lane*16.
__device__ __forceinline__ void gload16(const bf16* g, bf16* l) {
    __builtin_amdgcn_global_load_lds(
        (const __attribute__((address_space(1))) uint32_t*)g,
        (__attribute__((address_space(3))) uint32_t*)l, 16, 0, 0);
}

// pack two f32 -> u32 of 2 bf16 (elem0 = lo bits)
__device__ __forceinline__ unsigned pk2(float lo, float hi) {
    union { bf16 h[2]; unsigned u; } c;
    c.h[0] = (bf16)lo; c.h[1] = (bf16)hi;
    return c.u;
}
// raw v_exp_f32: 2^x
__device__ __forceinline__ float fexp2(float x) {
    float r;
    asm("v_exp_f32 %0, %1" : "=v"(r) : "v"(x));
    return r;
}
// v_max3_f32 (T17)
__device__ __forceinline__ float fmax3(float a, float b, float c) {
    float r;
    asm("v_max3_f32 %0, %1, %2, %3" : "=v"(r) : "v"(a), "v"(b), "v"(c));
    return r;
}

// bijective XCD chunk swizzle (nwg % 8 == 0)
__device__ __forceinline__ int xcd_swz(int id, int nwg) {
    return (id & 7) * (nwg >> 3) + (id >> 3);
}

#define SBAR()  __builtin_amdgcn_s_barrier()
#define SCHED() __builtin_amdgcn_sched_barrier(0)

// ---------------------------------------------------------------------------
// Fused weight prep: all 6 transposes+casts in ONE launch.
// ---------------------------------------------------------------------------
__global__ __launch_bounds__(256) void transpose_all(
    const float* __restrict__ wq, const float* __restrict__ wk,
    const float* __restrict__ wv, const float* __restrict__ wo,
    const float* __restrict__ w0, const float* __restrict__ w1,
    bf16* __restrict__ Wqkv, bf16* __restrict__ Wot,
    bf16* __restrict__ W0t, bf16* __restrict__ W1t)
{
    __shared__ float t[32][33];
    const int b = blockIdx.x;
    const float* src;
    bf16* dst;
    int K, N, tt;
    if (b < 1024)      { src = wq; dst = Wqkv;                       K = 1024; N = 1024; tt = b; }
    else if (b < 2048) { src = wk; dst = Wqkv + (size_t)1024 * 1024; K = 1024; N = 1024; tt = b - 1024; }
    else if (b < 3072) { src = wv; dst = Wqkv + (size_t)2048 * 1024; K = 1024; N = 1024; tt = b - 2048; }
    else if (b < 4096) { src = wo; dst = Wot;                        K = 1024; N = 1024; tt = b - 3072; }
    else if (b < 8192) { src = w0; dst = W0t;                        K = 1024; N = 4096; tt = b - 4096; }
    else               { src = w1; dst = W1t;                        K = 4096; N = 1024; tt = b - 8192; }
    const int ntx = N >> 5;
    const int n0 = (tt % ntx) * 32, k0 = (tt / ntx) * 32;
    const int tx = threadIdx.x, ty = threadIdx.y;
    #pragma unroll
    for (int i = ty; i < 32; i += 8)
        t[i][tx] = src[(size_t)(k0 + i) * N + n0 + tx];
    __syncthreads();
    #pragma unroll
    for (int i = ty; i < 32; i += 8)
        dst[(size_t)(n0 + i) * K + k0 + tx] = (bf16)t[tx][i];
}

// ---------------------------------------------------------------------------
// Batched bf16 transpose for V: src [Z][2048][64] -> dst [Z][64][2048]
// ---------------------------------------------------------------------------
__global__ __launch_bounds__(256) void transpose_v(
    const bf16* __restrict__ src, bf16* __restrict__ dst)
{
    __shared__ bf16 t[32][33];
    const int z = blockIdx.z;
    const int h0 = blockIdx.x * 32, s0 = blockIdx.y * 32;
    const bf16* sp = src + (size_t)z * 2048 * 64;
    bf16* dp = dst + (size_t)z * 64 * 2048;
    const int tx = threadIdx.x, ty = threadIdx.y;
    #pragma unroll
    for (int i = ty; i < 32; i += 8)
        t[i][tx] = sp[(size_t)(s0 + i) * 64 + h0 + tx];
    __syncthreads();
    #pragma unroll
    for (int i = ty; i < 32; i += 8)
        dp[(size_t)(h0 + i) * 2048 + s0 + tx] = t[tx][i];
}

// ---------------------------------------------------------------------------
// LayerNorm (D=1024) fp32 in -> bf16 out. One block (256 thr) per row.
// ---------------------------------------------------------------------------
__global__ __launch_bounds__(256) void ln_kernel(
    const float* __restrict__ x, const float* __restrict__ sc,
    const float* __restrict__ bi, bf16* __restrict__ y)
{
    const int row = blockIdx.x, tid = threadIdx.x;
    const f32x4 v = ((const f32x4*)(x + (size_t)row * 1024))[tid];
    float s  = v[0] + v[1] + v[2] + v[3];
    float s2 = v[0]*v[0] + v[1]*v[1] + v[2]*v[2] + v[3]*v[3];
    #pragma unroll
    for (int d = 1; d < 64; d <<= 1) {
        s  += __shfl_xor(s, d);
        s2 += __shfl_xor(s2, d);
    }
    __shared__ float red[8];
    if ((tid & 63) == 0) { red[tid >> 6] = s; red[4 + (tid >> 6)] = s2; }
    __syncthreads();
    s  = red[0] + red[1] + red[2] + red[3];
    s2 = red[4] + red[5] + red[6] + red[7];
    const float mu = s * (1.f / 1024.f);
    const float rstd = rsqrtf(s2 * (1.f / 1024.f) - mu * mu + 1e-6f);
    const f32x4 s4 = ((const f32x4*)sc)[tid];
    const f32x4 b4 = ((const f32x4*)bi)[tid];
    bf16x4 o;
    #pragma unroll
    for (int j = 0; j < 4; ++j)
        o[j] = (bf16)((v[j] - mu) * rstd * s4[j] + b4[j]);
    ((bf16x4*)(y + (size_t)row * 1024))[tid] = o;
}

// ---------------------------------------------------------------------------
// bf16 GEMM, dbuf + COUNTED vmcnt (R8-R12-validated loop), now with 3-bit
// both-sides XOR swizzle: physical chunk p of row r holds logical chunk
// p ^ (r&7)  (8 chunks of 8 elems per 64-col row) -> 2-way banks (free).
// ---------------------------------------------------------------------------
template <int EPI, int BM, int BN, int NW>
__global__ __launch_bounds__(NW * 64, 2) void gemm_kernel(
    const bf16* __restrict__ A, const bf16* __restrict__ Bt,
    int M, int N, int K,
    const float* __restrict__ b0, const float* __restrict__ b1,
    const float* __restrict__ b2, const float* __restrict__ res,
    bf16* __restrict__ o0, bf16* __restrict__ o1, bf16* __restrict__ o2,
    float* __restrict__ of)
{
    constexpr int NRW    = NW / 2;
    constexpr int MR     = BM / 32;
    constexpr int NR     = BN / 16 / NRW;
    constexpr int ACALLS = BM / (8 * NW);
    constexpr int BCALLS = BN / (8 * NW);
    constexpr int NLOADS = ACALLS + BCALLS;
    static_assert(NLOADS == 8 || NLOADS == 6, "vmcnt literal");
    __shared__ bf16 As[2][BM * 64];
    __shared__ bf16 Bs[2][BN * 64];

    const int tid = threadIdx.x;
    const int wave = tid >> 6, lane = tid & 63;
    const int wr = (wave / NRW) * (MR * 16), wc = (wave % NRW) * (NR * 16);
    const int lr = lane & 15, lg = lane >> 4;

    const int nwg = gridDim.x * gridDim.y;
    const int id = xcd_swz(blockIdx.y * gridDim.x + blockIdx.x, nwg);
    const int bm = (id / gridDim.x) * BM, bn = (id % gridDim.x) * BN;

    f32x4 acc[MR][NR] = {};

    // staging: thread t -> physical row t>>3 (+32/call), physical chunk t&7;
    // global chunk = (t&7) ^ (row&7)  (rows/call % 8 == 0 so row&7=(t>>3)&7)
    const int srow = tid >> 3;
    const int scol = (((tid & 7) ^ ((tid >> 3) & 7)) * 8);
    const bf16* Ag = A  + (size_t)(bm + srow) * K + scol;
    const bf16* Bg = Bt + (size_t)(bn + srow) * K + scol;

    auto stage = [&](int buf, int k0) {
        #pragma unroll
        for (int c = 0; c < ACALLS; ++c)
            gload16(Ag + (size_t)(c * 8 * NW) * K + k0,
                    &As[buf][(c * 8 * NW) * 64] + (size_t)tid * 8);
        #pragma unroll
        for (int c = 0; c < BCALLS; ++c)
            gload16(Bg + (size_t)(c * 8 * NW) * K + k0,
                    &Bs[buf][(c * 8 * NW) * 64] + (size_t)tid * 8);
    };

    // read: logical chunk (kh*4+lg) at physical ((kh*4+lg) ^ (lr&7))
    const int f3 = lane & 7;
    const int ko0 = ((0 + lg) ^ f3) * 8;     // kh = 0
    const int ko1 = ((4 + lg) ^ f3) * 8;     // kh = 1

    const int nk = K >> 6;
    stage(0, 0);
    __syncthreads();
    int cur = 0;
    for (int i = 0; i < nk; ++i) {
        if (i + 1 < nk) {
            stage(cur ^ 1, (i + 1) << 6);
            SCHED();
            if constexpr (NLOADS == 8)
                asm volatile("s_waitcnt vmcnt(8)" ::: "memory");
            else
                asm volatile("s_waitcnt vmcnt(6)" ::: "memory");
        } else {
            asm volatile("s_waitcnt vmcnt(0)" ::: "memory");
        }
        SCHED();
        SBAR();
        SCHED();
        #pragma unroll
        for (int kh = 0; kh < 2; ++kh) {
            const int ko = kh ? ko1 : ko0;
            bf16x8 a[MR], b[NR];
            #pragma unroll
            for (int m = 0; m < MR; ++m)
                a[m] = *(const bf16x8*)&As[cur][(wr + m * 16 + lr) * 64 + ko];
            #pragma unroll
            for (int n = 0; n < NR; ++n)
                b[n] = *(const bf16x8*)&Bs[cur][(wc + n * 16 + lr) * 64 + ko];
            #pragma unroll
            for (int m = 0; m < MR; ++m)
                #pragma unroll
                for (int n = 0; n < NR; ++n)
                    acc[m][n] = MFMA16(a[m], b[n], acc[m][n], 0, 0, 0);
        }
        SCHED();
        asm volatile("s_waitcnt lgkmcnt(0)" ::: "memory");
        SCHED();
        SBAR();
        SCHED();
        cur ^= 1;
    }

    const int rbase = bm + wr + (lg << 2);
    const int cbase = bn + wc + lr;
    #pragma unroll
    for (int m = 0; m < MR; ++m) {
        #pragma unroll
        for (int n = 0; n < NR; ++n) {
            const f32x4 v = acc[m][n];
            #pragma unroll
            for (int r = 0; r < 4; ++r) {
                const int row = rbase + m * 16 + r;
                const int col = cbase + n * 16;
                const float val = v[r];
                if constexpr (EPI == 0) {
                    const int which = col >> 10, cc = col & 1023;
                    const float* bp = (which == 0) ? b0 : (which == 1) ? b1 : b2;
                    bf16* dp = (which == 0) ? o0 : (which == 1) ? o1 : o2;
                    const float scl = (which == 0) ? 0.18033688011112042f : 1.0f;
                    const int bb = row >> 11, t = row & 2047;
                    const int nh = cc >> 6, hh = cc & 63;
                    dp[(((size_t)(bb * 16 + nh) * 2048 + t) << 6) + hh] =
                        (bf16)((val + bp[cc]) * scl);
                } else if constexpr (EPI == 1) {
                    of[(size_t)row * N + col] =
                        val + b0[col] + res[(size_t)row * N + col];
                } else {
                    const float xg = val + b0[col];
                    const float z2 = 1.5957691216f * (xg + 0.044715f * xg * xg * xg);
                    o0[(size_t)row * N + col] = (bf16)(xg / (1.f + __expf(-z2)));
                }
            }
        }
    }
}

// ---------------------------------------------------------------------------
// 256x256 8-phase bf16 GEMM (T2+T3+T4+T5), BK=64, 512 thr = 8 waves (2Mx4N).
// LDS halves split along K: As[slot][kh] = 256 rows x 32 kcols. Phase order
// per K-tile t: (kh0,mh0),(kh0,mh1),(kh1,mh0),(kh1,mh1) -> kh0 of slot t is
// dead after phase 1, so staging K(t+2).kh0 in phases 2/3 is race-free.
// Stage schedule: ph0->A[t+1].kh1  ph1->B[t+1].kh1  ph2->A[t+2].kh0
// ph3->B[t+2].kh0. Gates: vmcnt(8) end of ph1 & ph3 (the 2 needed halves
// are always the oldest of <=6 in flight); tail: vmcnt(4) at t=nk-2 ph3,
// vmcnt(0) at t=nk-1 ph1. 2-bit both-sides swizzle -> 2-way banks (free).
// EPI 2: bf16 gelu(acc + bias[col]); EPI 1: fp32 acc + bias + res.
// ---------------------------------------------------------------------------
template <int EPI>
__global__ __launch_bounds__(512, 2) void gemm256_kernel(
    const bf16* __restrict__ A, const bf16* __restrict__ Bt,
    int M, int N, int K,
    const float* __restrict__ b0, const float* __restrict__ res,
    bf16* __restrict__ o0, float* __restrict__ of)
{
    __shared__ bf16 As[2][2][256 * 32];
    __shared__ bf16 Bs[2][2][256 * 32];

    const int tid = threadIdx.x;
    const int wave = tid >> 6, lane = tid & 63;
    const int wm = wave >> 2, wn = wave & 3;     // 2M x 4N wave grid
    const int lr = lane & 15, lg = lane >> 4;

    const int nwg = gridDim.x * gridDim.y;
    const int id = xcd_swz(blockIdx.y * gridDim.x + blockIdx.x, nwg);
    const int bm = (id / gridDim.x) * 256, bn = (id % gridDim.x) * 256;

    f32x4 acc[8][4] = {};

    // staging: thread t -> physical row t>>2 (+128 on 2nd gload), chunk t&3;
    // global chunk = (t&3) ^ f2(row), f2(r) = (r ^ (r>>2)) & 3
    const int pr = tid >> 2;
    const int gc = ((tid & 3) ^ (pr & 3) ^ ((pr >> 2) & 3)) * 8;
    const bf16* Ag = A  + (size_t)(bm + pr) * K + gc;
    const bf16* Bg = Bt + (size_t)(bn + pr) * K + gc;

    auto stage_half = [&](int tile, int op, int kh) {
        const int slot = tile & 1;
        const int k0 = (tile << 6) + (kh << 5);
        const bf16* G = op ? Bg : Ag;
        bf16* L = op ? &Bs[slot][kh][0] : &As[slot][kh][0];
        gload16(G + k0, L + (size_t)tid * 8);
        gload16(G + (size_t)128 * K + k0, L + 4096 + (size_t)tid * 8);
    };

    // read: logical chunk lg at physical lg ^ f2(lr), f2 = (lr ^ (lr>>2)) & 3
    const int ko = ((lg ^ ((lane & 3) ^ ((lane >> 2) & 3))) * 8);

    const int nk = K >> 6;
    // prologue: A0.kh0 B0.kh0 A0.kh1 B0.kh1 A1.kh0 B1.kh0 (12 loads)
    stage_half(0, 0, 0); stage_half(0, 1, 0);
    stage_half(0, 0, 1); stage_half(0, 1, 1);
    stage_half(1, 0, 0); stage_half(1, 1, 0);
    SCHED();
    asm volatile("s_waitcnt vmcnt(8)" ::: "memory");   // A0/B0.kh0 landed
    SCHED(); SBAR(); SCHED();

    for (int t = 0; t < nk; ++t) {
        const int slot = t & 1;
        bf16x8 bR[4];
        #pragma unroll
        for (int ph = 0; ph < 4; ++ph) {
            const int kh = ph >> 1, mh = ph & 1;
            bf16x8 aR[4];
            #pragma unroll
            for (int m4 = 0; m4 < 4; ++m4)
                aR[m4] = *(const bf16x8*)
                    &As[slot][kh][(wm * 128 + mh * 64 + m4 * 16 + lr) * 32 + ko];
            if (mh == 0) {
                #pragma unroll
                for (int n = 0; n < 4; ++n)
                    bR[n] = *(const bf16x8*)
                        &Bs[slot][kh][(wn * 64 + n * 16 + lr) * 32 + ko];
            }
            if (ph == 0)      { if (t + 1 < nk) stage_half(t + 1, 0, 1); }
            else if (ph == 1) { if (t + 1 < nk) stage_half(t + 1, 1, 1); }
            else if (ph == 2) { if (t + 2 < nk) stage_half(t + 2, 0, 0); }
            else              { if (t + 2 < nk) stage_half(t + 2, 1, 0); }
            SCHED(); SBAR(); SCHED();
            asm volatile("s_waitcnt lgkmcnt(0)" ::: "memory");
            SCHED();
            __builtin_amdgcn_s_setprio(1);
            #pragma unroll
            for (int m4 = 0; m4 < 4; ++m4)
                #pragma unroll
                for (int n = 0; n < 4; ++n)
                    acc[mh * 4 + m4][n] =
                        MFMA16(aR[m4], bR[n], acc[mh * 4 + m4][n], 0, 0, 0);
            __builtin_amdgcn_s_setprio(0);
            SCHED();
            if (ph == 1) {
                if (t == nk - 1) asm volatile("s_waitcnt vmcnt(0)" ::: "memory");
                else             asm volatile("s_waitcnt vmcnt(8)" ::: "memory");
            } else if (ph == 3) {
                if (t == nk - 2)     asm volatile("s_waitcnt vmcnt(4)" ::: "memory");
                else if (t < nk - 2) asm volatile("s_waitcnt vmcnt(8)" ::: "memory");
            }
            SCHED(); SBAR(); SCHED();
        }
    }

    const int rbase = bm + wm * 128 + (lg << 2);
    const int cbase = bn + wn * 64 + lr;
    #pragma unroll
    for (int m = 0; m < 8; ++m) {
        #pragma unroll
        for (int n = 0; n < 4; ++n) {
            const f32x4 v = acc[m][n];
            #pragma unroll
            for (int r = 0; r < 4; ++r) {
                const int row = rbase + m * 16 + r;
                const int col = cbase + n * 16;
                const float val = v[r];
                if constexpr (EPI == 2) {
                    const float xg = val + b0[col];
                    const float z2 = 1.5957691216f * (xg + 0.044715f * xg * xg * xg);
                    o0[(size_t)row * N + col] = (bf16)(xg / (1.f + __expf(-z2)));
                } else {
                    of[(size_t)row * N + col] =
                        val + b0[col] + res[(size_t)row * N + col];
                }
            }
        }
    }
}

// ---------------------------------------------------------------------------
// Flash attention (R12-validated, unchanged): KVBLK=64, swapped-QK^T,
// in-register softmax, sigma-permuted V, l-via-ones-MFMA, direct-Q.
// ---------------------------------------------------------------------------
__global__ __launch_bounds__(256) void attn_kernel(
    const bf16* __restrict__ q, const bf16* __restrict__ k,
    const bf16* __restrict__ vt, bf16* __restrict__ enc)
{
    __shared__ bf16 Ks[64][72];
    __shared__ bf16 Vs[64][72];       // [h][sigma-permuted s-slot]

    const int tid = threadIdx.x, wave = tid >> 6, lane = tid & 63;
    const int lr = lane & 15, lk = (lane >> 4) * 8;
    const int qsel = (lane >> 4) << 2;
    const int id = xcd_swz(blockIdx.y * gridDim.x + blockIdx.x, 1024);
    const int qt = id % 32, z = id / 32;
    const bf16* qb = q + ((size_t)z * 2048 + qt * 64) * 64;
    const bf16* kb = k + (size_t)z * 2048 * 64;
    const bf16* vb = vt + (size_t)z * 64 * 2048;

    const int sr = tid >> 3, so = (tid & 7) * 8;
    const int vb0 = (so & 32) + ((so >> 4) & 1) * 4 + ((so >> 3) & 1) * 16;

    union V8 { bf16x8 v; bf16x4 h[2]; };
    bf16x8 kr0, kr1;
    V8 vr0, vr1;
    auto load_tile = [&](int st) {
        kr0 = *(const bf16x8*)&kb[(size_t)(st * 64 + sr) * 64 + so];
        kr1 = *(const bf16x8*)&kb[(size_t)(st * 64 + sr + 32) * 64 + so];
        vr0.v = *(const bf16x8*)&vb[(size_t)sr * 2048 + st * 64 + so];
        vr1.v = *(const bf16x8*)&vb[(size_t)(sr + 32) * 2048 + st * 64 + so];
    };
    auto write_tile = [&]() {
        *(bf16x8*)&Ks[sr][so]      = kr0;
        *(bf16x8*)&Ks[sr + 32][so] = kr1;
        *(bf16x4*)&Vs[sr][vb0]          = vr0.h[0];
        *(bf16x4*)&Vs[sr][vb0 + 8]      = vr0.h[1];
        *(bf16x4*)&Vs[sr + 32][vb0]     = vr1.h[0];
        *(bf16x4*)&Vs[sr + 32][vb0 + 8] = vr1.h[1];
    };

    load_tile(0);
    write_tile();
    const bf16x8 aq0 = *(const bf16x8*)&qb[(wave * 16 + lr) * 64 + lk];
    const bf16x8 aq1 = *(const bf16x8*)&qb[(wave * 16 + lr) * 64 + 32 + lk];
    __syncthreads();

    bf16x8 ones;
    #pragma unroll
    for (int i = 0; i < 8; ++i) ones[i] = (bf16)1.0f;

    float m_run = -1e30f;
    f32x4 accO[4] = {};
    f32x4 accL = {};

    for (int kt = 0; kt < 32; ++kt) {
        if (kt < 31) load_tile(kt + 1);

        f32x4 p4[4] = {};
        __builtin_amdgcn_s_setprio(1);
        #pragma unroll
        for (int j = 0; j < 4; ++j) {
            p4[j] = MFMA16(*(const bf16x8*)&Ks[j * 16 + lr][lk],      aq0, p4[j], 0, 0, 0);
            p4[j] = MFMA16(*(const bf16x8*)&Ks[j * 16 + lr][32 + lk], aq1, p4[j], 0, 0, 0);
        }
        __builtin_amdgcn_s_setprio(0);

        float pmax = fmax3(p4[0][0], p4[0][1], p4[0][2]);
        pmax = fmax3(pmax, p4[0][3], p4[1][0]);
        pmax = fmax3(pmax, p4[1][1], p4[1][2]);
        pmax = fmax3(pmax, p4[1][3], p4[2][0]);
        pmax = fmax3(pmax, p4[2][1], p4[2][2]);
        pmax = fmax3(pmax, p4[2][3], p4[3][0]);
        pmax = fmax3(pmax, p4[3][1], p4[3][2]);
        pmax = fmaxf(pmax, p4[3][3]);
        pmax = fmaxf(pmax, __shfl_xor(pmax, 16));
        pmax = fmaxf(pmax, __shfl_xor(pmax, 32));

        if (__any(pmax - m_run > 11.54f)) {
            const float mnew = fmaxf(m_run, pmax);
            const float fac = fexp2(m_run - mnew);
            m_run = mnew;
            float facq[4];
            #pragma unroll
            for (int r = 0; r < 4; ++r) facq[r] = __shfl(fac, qsel + r);
            #pragma unroll
            for (int nh = 0; nh < 4; ++nh)
                #pragma unroll
                for (int r = 0; r < 4; ++r) accO[nh][r] *= facq[r];
            #pragma unroll
            for (int r = 0; r < 4; ++r) accL[r] *= facq[r];
        }

        #pragma unroll
        for (int j = 0; j < 4; ++j)
            #pragma unroll
            for (int r = 0; r < 4; ++r)
                p4[j][r] = fexp2(p4[j][r] - m_run);

        union FW { unsigned u[4]; bf16x8 v; } f0, f1;
        f0.u[0] = pk2(p4[0][0], p4[0][1]);
        f0.u[1] = pk2(p4[0][2], p4[0][3]);
        f0.u[2] = pk2(p4[1][0], p4[1][1]);
        f0.u[3] = pk2(p4[1][2], p4[1][3]);
        f1.u[0] = pk2(p4[2][0], p4[2][1]);
        f1.u[1] = pk2(p4[2][2], p4[2][3]);
        f1.u[2] = pk2(p4[3][0], p4[3][1]);
        f1.u[3] = pk2(p4[3][2], p4[3][3]);

        __builtin_amdgcn_s_setprio(1);
        #pragma unroll
        for (int nh = 0; nh < 4; ++nh) {
            accO[nh] = MFMA16(f0.v, *(const bf16x8*)&Vs[nh * 16 + lr][lk],      accO[nh], 0, 0, 0);
            accO[nh] = MFMA16(f1.v, *(const bf16x8*)&Vs[nh * 16 + lr][32 + lk], accO[nh], 0, 0, 0);
        }
        accL = MFMA16(f0.v, ones, accL, 0, 0, 0);
        accL = MFMA16(f1.v, ones, accL, 0, 0, 0);
        __builtin_amdgcn_s_setprio(0);

        __syncthreads();
        if (kt < 31) write_tile();
        __syncthreads();
    }

    const int bb = z >> 4, nn = z & 15;
    #pragma unroll
    for (int nh = 0; nh < 4; ++nh)
        #pragma unroll
        for (int r = 0; r < 4; ++r) {
            const int t = qt * 64 + wave * 16 + qsel + r;
            const int hh = nh * 16 + lr;
            enc[((size_t)(bb * 2048 + t)) * 1024 + nn * 64 + hh] =
                (bf16)(accO[nh][r] / accL[r]);
        }
}

// ---------------------------------------------------------------------------
extern "C" void kernel_launch(void* const* d_in, const int* in_sizes, int n_in,
                              void* d_out, int out_size, void* d_ws, size_t ws_size,
                              hipStream_t stream) {
    const float* x    = (const float*)d_in[0];
    const float* ln0s = (const float*)d_in[1];
    const float* ln0b = (const float*)d_in[2];
    const float* ln1s = (const float*)d_in[3];
    const float* ln1b = (const float*)d_in[4];
    const float* wq   = (const float*)d_in[5];
    const float* bq   = (const float*)d_in[6];
    const float* wk   = (const float*)d_in[7];
    const float* bk   = (const float*)d_in[8];
    const float* wv   = (const float*)d_in[9];
    const float* bv   = (const float*)d_in[10];
    const float* wo   = (const float*)d_in[11];
    const float* bo   = (const float*)d_in[12];
    const float* w0   = (const float*)d_in[13];
    const float* b0   = (const float*)d_in[14];
    const float* w1   = (const float*)d_in[15];
    const float* b1   = (const float*)d_in[16];
    float* out = (float*)d_out;

    // workspace layout (128 MiB)
    char* p = (char*)d_ws;
    bf16* Wqkv = (bf16*)p; p += (size_t)3072 * 1024 * 2;
    bf16* Wot  = (bf16*)p; p += (size_t)1024 * 1024 * 2;
    bf16* W0t  = (bf16*)p; p += (size_t)4096 * 1024 * 2;
    bf16* W1t  = (bf16*)p; p += (size_t)1024 * 4096 * 2;
    bf16* y0   = (bf16*)p; p += (size_t)4096 * 1024 * 2;
    bf16* qbuf = (bf16*)p; p += (size_t)4096 * 1024 * 2;
    bf16* kbuf = (bf16*)p; p += (size_t)4096 * 1024 * 2;
    bf16* vbuf = (bf16*)p; p += (size_t)4096 * 1024 * 2;
    bf16* vtb  = (bf16*)p; p += (size_t)4096 * 1024 * 2;
    bf16* enc  = (bf16*)p; p += (size_t)4096 * 1024 * 2;
    float* x1  = (float*)p; p += (size_t)4096 * 1024 * 4;
    bf16* y1   = (bf16*)p; p += (size_t)4096 * 1024 * 2;
    bf16* h    = (bf16*)p; p += (size_t)4096 * 4096 * 2;

    const dim3 tb(32, 8);
    transpose_all<<<12288, tb, 0, stream>>>(wq, wk, wv, wo, w0, w1,
                                            Wqkv, Wot, W0t, W1t);

    ln_kernel<<<4096, 256, 0, stream>>>(x, ln0s, ln0b, y0);

    // fused QKV projection: [4096,1024] @ [1024,3072]
    gemm_kernel<0, 128, 128, 4><<<dim3(24, 32), 256, 0, stream>>>(
        y0, Wqkv, 4096, 3072, 1024, bq, bk, bv, nullptr, qbuf, kbuf, vbuf, nullptr);

    transpose_v<<<dim3(2, 64, 32), tb, 0, stream>>>(vbuf, vtb);

    attn_kernel<<<dim3(32, 32), 256, 0, stream>>>(qbuf, kbuf, vtb, enc);

    // out projection + residual -> x1 (fp32): 128x64 tile, 512 wg = 2/CU
    gemm_kernel<1, 128, 64, 4><<<dim3(16, 32), 256, 0, stream>>>(
        enc, Wot, 4096, 1024, 1024, bo, nullptr, nullptr, x, nullptr, nullptr, nullptr, x1);

    ln_kernel<<<4096, 256, 0, stream>>>(x1, ln1s, ln1b, y1);

    // MLP up + GELU -> h (bf16): 256^2 8-phase, grid 256 = 1 block/CU
    gemm256_kernel<2><<<dim3(16, 16), 512, 0, stream>>>(
        y1, W0t, 4096, 4096, 1024, b0, nullptr, h, nullptr);

    // MLP down + bias + residual -> out (fp32): 128x64 tile, 512 wg = 2/CU
    gemm_kernel<1, 128, 64, 4><<<dim3(16, 32), 256, 0, stream>>>(
        h, W1t, 4096, 1024, 4096, b1, nullptr, nullptr, x1, nullptr, nullptr, nullptr, out);
}